// Round 1
// baseline (896.955 us; speedup 1.0000x reference)
//
#include <hip/hip_runtime.h>
#include <hip/hip_bf16.h>
#include <math.h>

#define N_   4
#define LQ_  5440
#define D_   256
#define NH_  8
#define HD_  32
#define MQ_  (N_*LQ_)   // 21760 rows

// ---------------- GEMM: C[M,NC] = A[M,K] @ W[NC,K]^T (+bias) (+=C if ACCUM) ----
// fp32, 64x64 tile, 256 threads, 4x4 micro-tile. M%64==0, NC%64==0, K%16==0.
template<bool ACCUM>
__global__ __launch_bounds__(256)
void gemm_nt(const float* __restrict__ A, const float* __restrict__ W,
             const float* __restrict__ bias, float* __restrict__ C,
             int M, int NC, int K) {
  __shared__ float As[16][65];
  __shared__ float Ws[16][65];
  const int row0 = blockIdx.x * 64;
  const int col0 = blockIdx.y * 64;
  const int t  = threadIdx.x;
  const int tx = t & 15, ty = t >> 4;
  const int lm = t >> 2;          // 0..63: tile row loaded by this thread
  const int lk = (t & 3) * 4;     // 0,4,8,12: k-quad
  float acc[4][4] = {};
  for (int k0 = 0; k0 < K; k0 += 16) {
    float4 a = *reinterpret_cast<const float4*>(&A[(size_t)(row0 + lm) * K + k0 + lk]);
    float4 w = *reinterpret_cast<const float4*>(&W[(size_t)(col0 + lm) * K + k0 + lk]);
    As[lk+0][lm] = a.x; As[lk+1][lm] = a.y; As[lk+2][lm] = a.z; As[lk+3][lm] = a.w;
    Ws[lk+0][lm] = w.x; Ws[lk+1][lm] = w.y; Ws[lk+2][lm] = w.z; Ws[lk+3][lm] = w.w;
    __syncthreads();
    #pragma unroll
    for (int kk = 0; kk < 16; ++kk) {
      float av[4], wv[4];
      #pragma unroll
      for (int i = 0; i < 4; ++i) av[i] = As[kk][ty*4 + i];
      #pragma unroll
      for (int j = 0; j < 4; ++j) wv[j] = Ws[kk][tx*4 + j];
      #pragma unroll
      for (int i = 0; i < 4; ++i)
        #pragma unroll
        for (int j = 0; j < 4; ++j)
          acc[i][j] = fmaf(av[i], wv[j], acc[i][j]);
    }
    __syncthreads();
  }
  #pragma unroll
  for (int i = 0; i < 4; ++i) {
    const int r = row0 + ty*4 + i;
    const int c = col0 + tx*4;
    float4 v = make_float4(acc[i][0], acc[i][1], acc[i][2], acc[i][3]);
    if (bias) { v.x += bias[c+0]; v.y += bias[c+1]; v.z += bias[c+2]; v.w += bias[c+3]; }
    float4* cp = reinterpret_cast<float4*>(&C[(size_t)r * NC + c]);
    if (ACCUM) { float4 o = *cp; v.x += o.x; v.y += o.y; v.z += o.z; v.w += o.w; }
    *cp = v;
  }
}

// ------------- Wc[s][j][k] = sum_i W_agg[j, s*256+i] * W_out[i, k] -------------
__global__ __launch_bounds__(256)
void compute_wc(const float* __restrict__ W_agg, const float* __restrict__ W_out,
                float* __restrict__ Wc) {
  const int j = blockIdx.x, s = blockIdx.y, k = threadIdx.x;
  __shared__ float wrow[256];
  wrow[k] = W_agg[(size_t)j * 512 + s * 256 + k];
  __syncthreads();
  float acc = 0.f;
  for (int i = 0; i < 256; ++i)
    acc = fmaf(wrow[i], W_out[(size_t)i * 256 + k], acc);
  Wc[((size_t)s * 256 + j) * 256 + k] = acc;
}

// ---- b_fin[j] = b_agg[j] + sum_i (W_agg[j,i] + W_agg[j,256+i]) * b_out[i] -----
__global__ void compute_bfin(const float* __restrict__ W_agg,
                             const float* __restrict__ b_agg,
                             const float* __restrict__ b_out,
                             float* __restrict__ bfin) {
  const int j = threadIdx.x;
  float s = b_agg[j];
  for (int i = 0; i < 256; ++i)
    s = fmaf(W_agg[(size_t)j*512 + i] + W_agg[(size_t)j*512 + 256 + i], b_out[i], s);
  bfin[j] = s;
}

// ------------------------- deformable sampling --------------------------------
// one block per (n,q); thread t = (head h = t>>5, dim d = t&31)
// acc_out may alias off (off is fully staged into LDS before the write).
__global__ __launch_bounds__(256)
void deform_sample(const float* __restrict__ val,   // (N, LQ, 256)
                   const float* off,                 // (N*LQ, 256) logits-offsets
                   const float* attnl,               // (N*LQ, 128) attn logits
                   const float* __restrict__ refp,   // (N, LQ, 4, 2)
                   float* acc_out) {                 // (N*LQ, 256); may alias off
  const int row = blockIdx.x;
  const int n = row / LQ_;
  const int t = threadIdx.x;
  __shared__ float offs[256];
  __shared__ float aw[128];
  __shared__ float ref[8];
  offs[t] = off[(size_t)row * 256 + t];
  if (t < 128) aw[t]  = attnl[(size_t)row * 128 + t];
  if (t < 8)   ref[t] = refp[(size_t)row * 8 + t];
  __syncthreads();
  // per-head softmax over 16 (NL*NP) logits
  if (t < 8) {
    float mx = -1e30f;
    #pragma unroll
    for (int j = 0; j < 16; ++j) mx = fmaxf(mx, aw[t*16 + j]);
    float e[16], ssum = 0.f;
    #pragma unroll
    for (int j = 0; j < 16; ++j) { e[j] = expf(aw[t*16 + j] - mx); ssum += e[j]; }
    const float inv = 1.f / ssum;
    #pragma unroll
    for (int j = 0; j < 16; ++j) aw[t*16 + j] = e[j] * inv;
  }
  __syncthreads();
  const int h = t >> 5, d = t & 31;
  const float* vh = val + (size_t)n * LQ_ * D_ + h * HD_ + d;
  const int LS[4] = {64, 32, 16, 8};          // H == W per level
  const int LB[4] = {0, 4096, 5120, 5376};    // level base offsets
  float acc = 0.f;
  #pragma unroll
  for (int l = 0; l < 4; ++l) {
    const int   Wn = LS[l], Hn = LS[l];
    const float Wf = (float)Wn, Hf = (float)Hn;
    const float* vl = vh + (size_t)LB[l] * D_;
    const float rx = ref[l*2 + 0], ry = ref[l*2 + 1];
    #pragma unroll
    for (int p = 0; p < 4; ++p) {
      const int oi = ((h*4 + l)*4 + p) * 2;
      const float x = (rx + offs[oi+0] / Wf) * Wf - 0.5f;
      const float y = (ry + offs[oi+1] / Hf) * Hf - 0.5f;
      const float x0f = floorf(x), y0f = floorf(y);
      const int   x0 = (int)x0f,  y0 = (int)y0f;
      const float lx = x - x0f,   ly = y - y0f;
      const bool xv0 = (x0 >= 0)   && (x0 < Wn);
      const bool xv1 = (x0+1 >= 0) && (x0+1 < Wn);
      const bool yv0 = (y0 >= 0)   && (y0 < Hn);
      const bool yv1 = (y0+1 >= 0) && (y0+1 < Hn);
      float s = 0.f;
      if (xv0 && yv0) s = fmaf((1.f-lx)*(1.f-ly), vl[(size_t)(y0*Wn + x0    ) * D_], s);
      if (xv1 && yv0) s = fmaf(lx*(1.f-ly),       vl[(size_t)(y0*Wn + x0 + 1) * D_], s);
      if (xv0 && yv1) s = fmaf((1.f-lx)*ly,       vl[(size_t)((y0+1)*Wn + x0    ) * D_], s);
      if (xv1 && yv1) s = fmaf(lx*ly,             vl[(size_t)((y0+1)*Wn + x0 + 1) * D_], s);
      acc = fmaf(aw[h*16 + l*4 + p], s, acc);
    }
  }
  acc_out[(size_t)row * D_ + t] = acc;
}

// -------------------------------- launcher -------------------------------------
extern "C" void kernel_launch(void* const* d_in, const int* in_sizes, int n_in,
                              void* d_out, int out_size, void* d_ws, size_t ws_size,
                              hipStream_t stream) {
  const float* query0 = (const float*)d_in[0];
  const float* query1 = (const float*)d_in[1];
  const float* feat0  = (const float*)d_in[2];
  const float* feat1  = (const float*)d_in[3];
  const float* refp   = (const float*)d_in[4];
  const float* W_off  = (const float*)d_in[5];
  const float* b_off  = (const float*)d_in[6];
  const float* W_attn = (const float*)d_in[7];
  const float* b_attn = (const float*)d_in[8];
  const float* W_val  = (const float*)d_in[9];
  const float* b_val  = (const float*)d_in[10];
  const float* W_out  = (const float*)d_in[11];
  const float* b_out  = (const float*)d_in[12];
  const float* W_agg  = (const float*)d_in[13];
  const float* b_agg  = (const float*)d_in[14];
  float* out = (float*)d_out;

  float* ws = (float*)d_ws;
  const size_t SZ = (size_t)MQ_ * 256;
  float* val0 = ws;                          // value stream 0
  float* val1 = val0 + SZ;                   // value stream 1
  float* oa0  = val1 + SZ;                   // offsets -> then acc (aliased)
  float* oa1  = oa0 + SZ;
  float* at0  = oa1 + SZ;                    // attn logits (MQ*128)
  float* at1  = at0 + (size_t)MQ_ * 128;
  float* Wc   = at1 + (size_t)MQ_ * 128;     // 2*256*256 combined out+agg weights
  float* bfin = Wc + 2 * 256 * 256;          // 256

  const dim3 g256(MQ_/64, 4), g128(MQ_/64, 2);
  // projections
  gemm_nt<false><<<g256, 256, 0, stream>>>(feat0,  W_val,  b_val,  val0, MQ_, 256, 256);
  gemm_nt<false><<<g256, 256, 0, stream>>>(feat1,  W_val,  b_val,  val1, MQ_, 256, 256);
  gemm_nt<false><<<g256, 256, 0, stream>>>(query0, W_off,  b_off,  oa0,  MQ_, 256, 256);
  gemm_nt<false><<<g256, 256, 0, stream>>>(query1, W_off,  b_off,  oa1,  MQ_, 256, 256);
  gemm_nt<false><<<g128, 256, 0, stream>>>(query0, W_attn, b_attn, at0,  MQ_, 128, 256);
  gemm_nt<false><<<g128, 256, 0, stream>>>(query1, W_attn, b_attn, at1,  MQ_, 128, 256);
  // fold out-proj into agg: Wc_s = W_agg[:, s*256:(s+1)*256] @ W_out
  compute_wc  <<<dim3(256, 2), 256, 0, stream>>>(W_agg, W_out, Wc);
  compute_bfin<<<1, 256, 0, stream>>>(W_agg, b_agg, b_out, bfin);
  // sampling (acc written in place of offsets)
  deform_sample<<<MQ_, 256, 0, stream>>>(val0, oa0, at0, refp, oa0);
  deform_sample<<<MQ_, 256, 0, stream>>>(val1, oa1, at1, refp, oa1);
  // final: out = acc0 @ Wc0^T + b_fin + acc1 @ Wc1^T
  gemm_nt<false><<<g256, 256, 0, stream>>>(oa0, Wc,           bfin,    out, MQ_, 256, 256);
  gemm_nt<true> <<<g256, 256, 0, stream>>>(oa1, Wc + 256*256, nullptr, out, MQ_, 256, 256);
}

// Round 2
// 416.119 us; speedup vs baseline: 2.1555x; 2.1555x over previous
//
#include <hip/hip_runtime.h>
#include <hip/hip_bf16.h>
#include <math.h>

#define N_   4
#define LQ_  5440
#define D_   256
#define MQ_  (N_*LQ_)   // 21760 rows, 21760/128 = 170 exact

typedef __bf16  bf16x8 __attribute__((ext_vector_type(8)));
typedef float   f32x4  __attribute__((ext_vector_type(4)));

__device__ __forceinline__ unsigned short f2b(float f) {
  union { float f; unsigned u; } v; v.f = f;
  unsigned r = v.u + 0x7FFFu + ((v.u >> 16) & 1u);   // RNE
  return (unsigned short)(r >> 16);
}
__device__ __forceinline__ float b2f(unsigned short u) {
  union { unsigned u; float f; } v; v.u = ((unsigned)u) << 16; return v.f;
}

#define GLD16(gp, lp) __builtin_amdgcn_global_load_lds( \
    (const __attribute__((address_space(1))) void*)(gp), \
    (__attribute__((address_space(3))) void*)(lp), 16, 0, 0)

// -------- fp32 -> bf16 convert (4 elems/thread, grid-stride) -------------------
__global__ __launch_bounds__(256)
void cvt_bf16(const float* __restrict__ in, unsigned short* __restrict__ out, int n4) {
  int i = blockIdx.x * blockDim.x + threadIdx.x;
  const int stride = gridDim.x * blockDim.x;
  for (; i < n4; i += stride) {
    float4 v = reinterpret_cast<const float4*>(in)[i];
    ushort4 o;
    o.x = f2b(v.x); o.y = f2b(v.y); o.z = f2b(v.z); o.w = f2b(v.w);
    reinterpret_cast<ushort4*>(out)[i] = o;
  }
}

// -------- bf16 MFMA GEMM: C[M,NC] = A[M,K] @ W[NC,K]^T + bias ------------------
// 128x128 tile, BK=64, 256 threads (4 waves, 2x2 wave grid, 64x64 per wave).
// global_load_lds(16B) staging with XOR chunk swizzle (write-source + read, T2/rule21).
template<bool OUT_BF16>
__global__ __launch_bounds__(256)
void gemm_bf16_nt(const unsigned short* __restrict__ A,
                  const unsigned short* __restrict__ W,
                  const float* __restrict__ bias, void* __restrict__ Cv,
                  int M, int NC, int K) {
  __shared__ __align__(16) unsigned short As[128 * 64];
  __shared__ __align__(16) unsigned short Ws[128 * 64];
  const int t    = threadIdx.x;
  const int lane = t & 63;
  const int wv   = t >> 6;
  const int wr   = wv >> 1, wc = wv & 1;
  const int row0 = blockIdx.x * 128, col0 = blockIdx.y * 128;

  const int srow   = t >> 3;                 // + i*32 per issue
  const int schunk = t & 7;
  const int wbase  = wv * 512;               // wave-uniform LDS elem base (+ i*2048)

  f32x4 acc[4][4] = {};

  for (int k0 = 0; k0 < K; k0 += 64) {
    __syncthreads();                          // previous compute done before overwrite
    #pragma unroll
    for (int i = 0; i < 4; ++i) {
      const int row = i * 32 + srow;
      const int ch  = schunk ^ (row & 7);     // pre-swizzled global source
      GLD16(A + (size_t)(row0 + row) * K + k0 + ch * 8, &As[i * 2048 + wbase]);
      GLD16(W + (size_t)(col0 + row) * K + k0 + ch * 8, &Ws[i * 2048 + wbase]);
    }
    __syncthreads();                          // drains vmcnt (global_load_lds)

    bf16x8 af[4][2], bf[4][2];
    #pragma unroll
    for (int f = 0; f < 4; ++f)
      #pragma unroll
      for (int kk = 0; kk < 2; ++kk) {
        const int ra = wr * 64 + f * 16 + (lane & 15);
        const int ca = (kk * 4 + (lane >> 4)) ^ (ra & 7);   // swizzled read
        af[f][kk] = *(const bf16x8*)&As[ra * 64 + ca * 8];
        const int rb = wc * 64 + f * 16 + (lane & 15);
        const int cb = (kk * 4 + (lane >> 4)) ^ (rb & 7);
        bf[f][kk] = *(const bf16x8*)&Ws[rb * 64 + cb * 8];
      }
    #pragma unroll
    for (int kk = 0; kk < 2; ++kk)
      #pragma unroll
      for (int fm = 0; fm < 4; ++fm)
        #pragma unroll
        for (int fn = 0; fn < 4; ++fn)
          acc[fm][fn] = __builtin_amdgcn_mfma_f32_16x16x32_bf16(
              af[fm][kk], bf[fn][kk], acc[fm][fn], 0, 0, 0);
  }

  // epilogue: D col = lane&15, row = (lane>>4)*4 + r  [verified layout]
  #pragma unroll
  for (int fm = 0; fm < 4; ++fm) {
    const int m = row0 + wr * 64 + fm * 16 + (lane >> 4) * 4;
    #pragma unroll
    for (int fn = 0; fn < 4; ++fn) {
      const int c = col0 + wc * 64 + fn * 16 + (lane & 15);
      const float bv = bias ? bias[c] : 0.f;
      #pragma unroll
      for (int r = 0; r < 4; ++r) {
        const float v = acc[fm][fn][r] + bv;
        if (OUT_BF16) ((unsigned short*)Cv)[(size_t)(m + r) * NC + c] = f2b(v);
        else          ((float*)Cv)[(size_t)(m + r) * NC + c] = v;
      }
    }
  }
}

// ------------- Wfin[j][s*256+k] = sum_i W_agg[j, s*256+i] * W_out[i, k] --------
__global__ __launch_bounds__(256)
void compute_wc(const float* __restrict__ W_agg, const float* __restrict__ W_out,
                unsigned short* __restrict__ Wfin) {
  const int j = blockIdx.x, s = blockIdx.y, k = threadIdx.x;
  __shared__ float wrow[256];
  wrow[k] = W_agg[(size_t)j * 512 + s * 256 + k];
  __syncthreads();
  float acc = 0.f;
  for (int i = 0; i < 256; ++i)
    acc = fmaf(wrow[i], W_out[(size_t)i * 256 + k], acc);
  Wfin[(size_t)j * 512 + s * 256 + k] = f2b(acc);
}

// ---- b_fin[j] = b_agg[j] + sum_i (W_agg[j,i] + W_agg[j,256+i]) * b_out[i] -----
__global__ void compute_bfin(const float* __restrict__ W_agg,
                             const float* __restrict__ b_agg,
                             const float* __restrict__ b_out,
                             float* __restrict__ bfin) {
  const int j = threadIdx.x;
  float s = b_agg[j];
  for (int i = 0; i < 256; ++i)
    s = fmaf(W_agg[(size_t)j * 512 + i] + W_agg[(size_t)j * 512 + 256 + i], b_out[i], s);
  bfin[j] = s;
}

__global__ void prep_bcat(const float* __restrict__ b_off,
                          const float* __restrict__ b_attn, float* __restrict__ bcat) {
  const int t = threadIdx.x;  // 384
  bcat[t] = (t < 256) ? b_off[t] : b_attn[t - 256];
}

// ------------------------- deformable sampling (both streams) ------------------
// grid (MQ, 2); block 256. Phase 1: 128 threads, one (h,l,p) point each ->
// softmax (16-lane shfl) + 4 clamped corner indices + combined weights into LDS.
// Phase 2: 256 threads (h=t>>5, d=t&31) gather bf16 values + fma only.
__global__ __launch_bounds__(256)
void deform_sample2(const unsigned short* __restrict__ vals,  // (2, N, LQ, 256) bf16
                    const unsigned short* __restrict__ oa,    // (2, MQ, 384) bf16
                    const float* __restrict__ refp,           // (N, LQ, 4, 2)
                    unsigned short* __restrict__ acc_out) {   // (MQ, 512) bf16
  const int row = blockIdx.x;
  const int s   = blockIdx.y;
  const int n   = row / LQ_;
  const int t   = threadIdx.x;
  __shared__ int   pidx[128][4];
  __shared__ float pw[128][4];
  const unsigned short* oar = oa + ((size_t)s * MQ_ + row) * 384;

  if (t < 128) {
    const int l = (t >> 2) & 3;
    const int LSa[4] = {64, 32, 16, 8};
    const int LBa[4] = {0, 4096, 5120, 5376};
    const int   Wn = LSa[l];
    const float Wf = (float)Wn;
    const float ox = b2f(oar[t * 2]);
    const float oy = b2f(oar[t * 2 + 1]);
    const float rx = refp[((size_t)row * 4 + l) * 2 + 0];
    const float ry = refp[((size_t)row * 4 + l) * 2 + 1];
    const float x = fmaf(rx, Wf, ox) - 0.5f;
    const float y = fmaf(ry, Wf, oy) - 0.5f;
    const float x0f = floorf(x), y0f = floorf(y);
    const int   x0 = (int)x0f,   y0 = (int)y0f;
    const float lx = x - x0f,    ly = y - y0f;
    // softmax over the 16 (l,p) logits of this head (16-lane subgroup)
    float logit = b2f(oar[256 + t]);
    float mx = logit;
    #pragma unroll
    for (int dd = 1; dd < 16; dd <<= 1) mx = fmaxf(mx, __shfl_xor(mx, dd));
    const float e = __expf(logit - mx);
    float se = e;
    #pragma unroll
    for (int dd = 1; dd < 16; dd <<= 1) se += __shfl_xor(se, dd);
    const float aw = e / se;
    const int   xs[2] = {x0, x0 + 1}, ys[2] = {y0, y0 + 1};
    const float wx[2] = {1.f - lx, lx}, wy[2] = {1.f - ly, ly};
    #pragma unroll
    for (int cy = 0; cy < 2; ++cy)
      #pragma unroll
      for (int cx = 0; cx < 2; ++cx) {
        const int xi = xs[cx], yi = ys[cy];
        const bool v = (xi >= 0) && (xi < Wn) && (yi >= 0) && (yi < Wn);
        const int xc = min(max(xi, 0), Wn - 1), yc = min(max(yi, 0), Wn - 1);
        pidx[t][cy * 2 + cx] = LBa[l] + yc * Wn + xc;
        pw[t][cy * 2 + cx]   = v ? wx[cx] * wy[cy] * aw : 0.f;
      }
  }
  __syncthreads();

  const int h = t >> 5, d = t & 31;
  const unsigned short* vh = vals + ((size_t)s * N_ + n) * LQ_ * 256 + h * 32 + d;
  float acc = 0.f;
  #pragma unroll
  for (int j = 0; j < 16; ++j) {
    const int pi = h * 16 + j;
    #pragma unroll
    for (int c = 0; c < 4; ++c)
      acc = fmaf(pw[pi][c], b2f(vh[(size_t)pidx[pi][c] * 256]), acc);
  }
  acc_out[(size_t)row * 512 + s * 256 + t] = f2b(acc);
}

// -------------------------------- launcher -------------------------------------
extern "C" void kernel_launch(void* const* d_in, const int* in_sizes, int n_in,
                              void* d_out, int out_size, void* d_ws, size_t ws_size,
                              hipStream_t stream) {
  const float* query0 = (const float*)d_in[0];
  const float* query1 = (const float*)d_in[1];
  const float* feat0  = (const float*)d_in[2];
  const float* feat1  = (const float*)d_in[3];
  const float* refp   = (const float*)d_in[4];
  const float* W_off  = (const float*)d_in[5];
  // d_in[6] = b_off
  const float* W_attn = (const float*)d_in[7];
  // d_in[8] = b_attn
  const float* W_val  = (const float*)d_in[9];
  const float* b_val  = (const float*)d_in[10];
  const float* W_out  = (const float*)d_in[11];
  const float* b_out  = (const float*)d_in[12];
  const float* W_agg  = (const float*)d_in[13];
  const float* b_agg  = (const float*)d_in[14];
  float* out = (float*)d_out;

  char* p = (char*)d_ws;
  const size_t SZ2 = (size_t)MQ_ * 256 * 2;            // bf16 (MQ,256)
  unsigned short* qb   = (unsigned short*)p; p += 2 * SZ2;            // qb0, qb1
  unsigned short* fb   = (unsigned short*)p; p += 2 * SZ2;            // fb0, fb1 -> acc overlay
  unsigned short* valb = (unsigned short*)p; p += 2 * SZ2;            // val bf16, both streams
  unsigned short* oab  = (unsigned short*)p; p += (size_t)2 * MQ_ * 384 * 2;
  unsigned short* Wvalb = (unsigned short*)p; p += 256 * 256 * 2;
  unsigned short* Wcatb = (unsigned short*)p; p += 384 * 256 * 2;
  unsigned short* Wfinb = (unsigned short*)p; p += 256 * 512 * 2;
  float* bcat = (float*)p; p += 384 * 4;
  float* bfin = (float*)p; p += 256 * 4;
  unsigned short* acc = fb;                            // overlay: (MQ,512) bf16

  const int n4 = MQ_ * 256 / 4;
  cvt_bf16<<<2048, 256, 0, stream>>>(query0, qb,            n4);
  cvt_bf16<<<2048, 256, 0, stream>>>(query1, qb + MQ_*256,  n4);
  cvt_bf16<<<2048, 256, 0, stream>>>(feat0,  fb,            n4);
  cvt_bf16<<<2048, 256, 0, stream>>>(feat1,  fb + MQ_*256,  n4);
  cvt_bf16<<<64,   256, 0, stream>>>(W_val,  Wvalb, 256*256/4);
  cvt_bf16<<<64,   256, 0, stream>>>(W_off,  Wcatb, 256*256/4);
  cvt_bf16<<<32,   256, 0, stream>>>(W_attn, Wcatb + 256*256, 128*256/4);
  prep_bcat<<<1, 384, 0, stream>>>((const float*)d_in[6], (const float*)d_in[8], bcat);
  compute_wc  <<<dim3(256, 2), 256, 0, stream>>>(W_agg, W_out, Wfinb);
  compute_bfin<<<1, 256, 0, stream>>>(W_agg, b_agg, b_out, bfin);

  // value projections (bf16 out)
  gemm_bf16_nt<true><<<dim3(170, 2), 256, 0, stream>>>(fb,           Wvalb, b_val, valb,            MQ_, 256, 256);
  gemm_bf16_nt<true><<<dim3(170, 2), 256, 0, stream>>>(fb + MQ_*256, Wvalb, b_val, valb + MQ_*256,  MQ_, 256, 256);
  // fused offset+attn projections (bf16 out)
  gemm_bf16_nt<true><<<dim3(170, 3), 256, 0, stream>>>(qb,           Wcatb, bcat, oab,                MQ_, 384, 256);
  gemm_bf16_nt<true><<<dim3(170, 3), 256, 0, stream>>>(qb + MQ_*256, Wcatb, bcat, oab + (size_t)MQ_*384, MQ_, 384, 256);
  // sampling, both streams, acc interleaved (MQ,512)
  deform_sample2<<<dim3(MQ_, 2), 256, 0, stream>>>(valb, oab, refp, acc);
  // final fused out+agg projection: K=512
  gemm_bf16_nt<false><<<dim3(170, 2), 256, 0, stream>>>(acc, Wfinb, bfin, out, MQ_, 256, 512);
}

// Round 3
// 195.338 us; speedup vs baseline: 4.5918x; 2.1303x over previous
//
#include <hip/hip_runtime.h>
#include <hip/hip_bf16.h>
#include <math.h>

#define N_   4
#define LQ_  5440
#define D_   256
#define MQ_  (N_*LQ_)   // 21760 rows; /8 = 2720 blocks; /128 = 170 tiles

typedef __bf16  bf16x8 __attribute__((ext_vector_type(8)));
typedef float   f32x4  __attribute__((ext_vector_type(4)));

__device__ __forceinline__ unsigned short f2b(float f) {
  union { float f; unsigned u; } v; v.f = f;
  unsigned r = v.u + 0x7FFFu + ((v.u >> 16) & 1u);   // RNE
  return (unsigned short)(r >> 16);
}
__device__ __forceinline__ float b2f(unsigned short u) {
  union { unsigned u; float f; } v; v.u = ((unsigned)u) << 16; return v.f;
}
__device__ __forceinline__ float lo2f(unsigned u) {
  union { unsigned u; float f; } v; v.u = u << 16; return v.f;
}
__device__ __forceinline__ float hi2f(unsigned u) {
  union { unsigned u; float f; } v; v.u = u & 0xffff0000u; return v.f;
}

#define GLD16(gp, lp) __builtin_amdgcn_global_load_lds( \
    (const __attribute__((address_space(1))) void*)(gp), \
    (__attribute__((address_space(3))) void*)(lp), 16, 0, 0)

// -------- fp32 -> bf16 convert, 4 tensors in one dispatch ----------------------
__global__ __launch_bounds__(256)
void cvt_bf16_4(const float* __restrict__ p0, const float* __restrict__ p1,
                const float* __restrict__ p2, const float* __restrict__ p3,
                unsigned short* __restrict__ out, int n4) {
  const float* srcs[4] = {p0, p1, p2, p3};
  const float* in = srcs[blockIdx.y];
  unsigned short* o = out + (size_t)blockIdx.y * n4 * 4;
  int i = blockIdx.x * blockDim.x + threadIdx.x;
  const int stride = gridDim.x * blockDim.x;
  for (; i < n4; i += stride) {
    float4 v = reinterpret_cast<const float4*>(in)[i];
    ushort4 r;
    r.x = f2b(v.x); r.y = f2b(v.y); r.z = f2b(v.z); r.w = f2b(v.w);
    reinterpret_cast<ushort4*>(o)[i] = r;
  }
}

__global__ __launch_bounds__(256)
void cvt_bf16(const float* __restrict__ in, unsigned short* __restrict__ out, int n4) {
  int i = blockIdx.x * blockDim.x + threadIdx.x;
  const int stride = gridDim.x * blockDim.x;
  for (; i < n4; i += stride) {
    float4 v = reinterpret_cast<const float4*>(in)[i];
    ushort4 o;
    o.x = f2b(v.x); o.y = f2b(v.y); o.z = f2b(v.z); o.w = f2b(v.w);
    reinterpret_cast<ushort4*>(out)[i] = o;
  }
}

// -------- bf16 MFMA GEMM: C[M,NC] = A[M,K] @ W[NC,K]^T + bias ------------------
// 128x128 tile, BK=64, 256 threads. blockIdx.z batches streams (A/C strides).
template<bool OUT_BF16>
__global__ __launch_bounds__(256)
void gemm_bf16_nt(const unsigned short* __restrict__ A,
                  const unsigned short* __restrict__ W,
                  const float* __restrict__ bias, void* __restrict__ Cv,
                  int M, int NC, int K, size_t zsA, size_t zsC) {
  __shared__ __align__(16) unsigned short As[128 * 64];
  __shared__ __align__(16) unsigned short Ws[128 * 64];
  A += zsA * blockIdx.z;
  const int t    = threadIdx.x;
  const int lane = t & 63;
  const int wv   = t >> 6;
  const int wr   = wv >> 1, wc = wv & 1;
  const int row0 = blockIdx.x * 128, col0 = blockIdx.y * 128;

  const int srow   = t >> 3;
  const int schunk = t & 7;
  const int wbase  = wv * 512;

  f32x4 acc[4][4] = {};

  for (int k0 = 0; k0 < K; k0 += 64) {
    __syncthreads();
    #pragma unroll
    for (int i = 0; i < 4; ++i) {
      const int row = i * 32 + srow;
      const int ch  = schunk ^ (row & 7);
      GLD16(A + (size_t)(row0 + row) * K + k0 + ch * 8, &As[i * 2048 + wbase]);
      GLD16(W + (size_t)(col0 + row) * K + k0 + ch * 8, &Ws[i * 2048 + wbase]);
    }
    __syncthreads();

    bf16x8 af[4][2], bf[4][2];
    #pragma unroll
    for (int f = 0; f < 4; ++f)
      #pragma unroll
      for (int kk = 0; kk < 2; ++kk) {
        const int ra = wr * 64 + f * 16 + (lane & 15);
        const int ca = (kk * 4 + (lane >> 4)) ^ (ra & 7);
        af[f][kk] = *(const bf16x8*)&As[ra * 64 + ca * 8];
        const int rb = wc * 64 + f * 16 + (lane & 15);
        const int cb = (kk * 4 + (lane >> 4)) ^ (rb & 7);
        bf[f][kk] = *(const bf16x8*)&Ws[rb * 64 + cb * 8];
      }
    #pragma unroll
    for (int kk = 0; kk < 2; ++kk)
      #pragma unroll
      for (int fm = 0; fm < 4; ++fm)
        #pragma unroll
        for (int fn = 0; fn < 4; ++fn)
          acc[fm][fn] = __builtin_amdgcn_mfma_f32_16x16x32_bf16(
              af[fm][kk], bf[fn][kk], acc[fm][fn], 0, 0, 0);
  }

  #pragma unroll
  for (int fm = 0; fm < 4; ++fm) {
    const int m = row0 + wr * 64 + fm * 16 + (lane >> 4) * 4;
    #pragma unroll
    for (int fn = 0; fn < 4; ++fn) {
      const int c = col0 + wc * 64 + fn * 16 + (lane & 15);
      const float bv = bias ? bias[c] : 0.f;
      #pragma unroll
      for (int r = 0; r < 4; ++r) {
        const float v = acc[fm][fn][r] + bv;
        if (OUT_BF16)
          ((unsigned short*)Cv)[zsC * blockIdx.z + (size_t)(m + r) * NC + c] = f2b(v);
        else
          ((float*)Cv)[zsC * blockIdx.z + (size_t)(m + r) * NC + c] = v;
      }
    }
  }
}

// ------------- Wfin[j][s*256+k] = sum_i W_agg[j, s*256+i] * W_out[i, k] --------
__global__ __launch_bounds__(256)
void compute_wc(const float* __restrict__ W_agg, const float* __restrict__ W_out,
                unsigned short* __restrict__ Wfin) {
  const int j = blockIdx.x, s = blockIdx.y, k = threadIdx.x;
  __shared__ float wrow[256];
  wrow[k] = W_agg[(size_t)j * 512 + s * 256 + k];
  __syncthreads();
  float acc = 0.f;
  for (int i = 0; i < 256; ++i)
    acc = fmaf(wrow[i], W_out[(size_t)i * 256 + k], acc);
  Wfin[(size_t)j * 512 + s * 256 + k] = f2b(acc);
}

__global__ void compute_bfin(const float* __restrict__ W_agg,
                             const float* __restrict__ b_agg,
                             const float* __restrict__ b_out,
                             float* __restrict__ bfin) {
  const int j = threadIdx.x;
  float s = b_agg[j];
  for (int i = 0; i < 256; ++i)
    s = fmaf(W_agg[(size_t)j * 512 + i] + W_agg[(size_t)j * 512 + 256 + i], b_out[i], s);
  bfin[j] = s;
}

__global__ void prep_bcat(const float* __restrict__ b_off,
                          const float* __restrict__ b_attn, float* __restrict__ bcat) {
  const int t = threadIdx.x;  // 384
  bcat[t] = (t < 256) ? b_off[t] : b_attn[t - 256];
}

// ------------------------- deformable sampling (both streams) ------------------
// grid (MQ/8, 2); block 256 = 8 queries x 32 threads.
// Phase 1: per query, 32 threads x 4 points (k-loop): softmax (16-lane shfl) +
//          4 clamped corner indices + combined validity*bilinear*attn weights.
//          LDS layout [q][j][h][4] so phase-2's 8 h-lanes read contiguous 128B.
// Phase 2: thread=(q, h=tq>>2, dg=tq&3): 16 pts x 4 corners x uint4 (8 bf16) gather.
__global__ __launch_bounds__(256)
void deform_sample2(const unsigned short* __restrict__ vals,  // (2, N, LQ, 256) bf16
                    const unsigned short* __restrict__ oa,    // (2, MQ, 384) bf16
                    const float* __restrict__ refp,           // (N, LQ, 4, 2)
                    unsigned short* __restrict__ acc_out) {   // (MQ, 512) bf16
  const int s  = blockIdx.y;
  const int t  = threadIdx.x;
  const int q  = t >> 5, tq = t & 31;
  const int row = blockIdx.x * 8 + q;
  const int n  = row / LQ_;
  __shared__ int   pidxT[8][16][8][4];
  __shared__ float pwT[8][16][8][4];

  const unsigned short* oar = oa + ((size_t)s * MQ_ + row) * 384;
  {
    const int LSa[4] = {64, 32, 16, 8};
    const int LBa[4] = {0, 4096, 5120, 5376};
    #pragma unroll
    for (int k = 0; k < 4; ++k) {
      const int pp = tq + 32 * k;               // point id: h=pp>>4, l=(pp>>2)&3
      const int l  = (pp >> 2) & 3;
      const int   Wn = LSa[l];
      const float Wf = (float)Wn;
      const float ox = b2f(oar[pp * 2]);
      const float oy = b2f(oar[pp * 2 + 1]);
      const float rx = refp[((size_t)row * 4 + l) * 2 + 0];
      const float ry = refp[((size_t)row * 4 + l) * 2 + 1];
      const float x = fmaf(rx, Wf, ox) - 0.5f;
      const float y = fmaf(ry, Wf, oy) - 0.5f;
      const float x0f = floorf(x), y0f = floorf(y);
      const int   x0 = (int)x0f,   y0 = (int)y0f;
      const float lx = x - x0f,    ly = y - y0f;
      // softmax over this head's 16 logits: lanes (tq&~15)..+15 hold them
      float logit = b2f(oar[256 + pp]);
      float mx = logit;
      #pragma unroll
      for (int dd = 1; dd < 16; dd <<= 1) mx = fmaxf(mx, __shfl_xor(mx, dd));
      const float e = __expf(logit - mx);
      float se = e;
      #pragma unroll
      for (int dd = 1; dd < 16; dd <<= 1) se += __shfl_xor(se, dd);
      const float aw = e / se;
      const int   xs[2] = {x0, x0 + 1}, ys[2] = {y0, y0 + 1};
      const float wx[2] = {1.f - lx, lx}, wy[2] = {1.f - ly, ly};
      const int jj = pp & 15, hh = pp >> 4;
      #pragma unroll
      for (int cy = 0; cy < 2; ++cy)
        #pragma unroll
        for (int cx = 0; cx < 2; ++cx) {
          const int xi = xs[cx], yi = ys[cy];
          const bool v = (xi >= 0) && (xi < Wn) && (yi >= 0) && (yi < Wn);
          const int xc = min(max(xi, 0), Wn - 1), yc = min(max(yi, 0), Wn - 1);
          pidxT[q][jj][hh][cy * 2 + cx] = LBa[l] + yc * Wn + xc;
          pwT[q][jj][hh][cy * 2 + cx]   = v ? wx[cx] * wy[cy] * aw : 0.f;
        }
    }
  }
  __syncthreads();

  const int h = tq >> 2, dg = tq & 3;
  const unsigned short* vh = vals + ((size_t)s * N_ + n) * LQ_ * 256 + h * 32 + dg * 8;
  float acc[8] = {};
  #pragma unroll
  for (int j = 0; j < 16; ++j) {
    const int4  idx = *reinterpret_cast<const int4*>(&pidxT[q][j][h][0]);
    const float4 w  = *reinterpret_cast<const float4*>(&pwT[q][j][h][0]);
    const int ia[4] = {idx.x, idx.y, idx.z, idx.w};
    const float wa[4] = {w.x, w.y, w.z, w.w};
    #pragma unroll
    for (int c = 0; c < 4; ++c) {
      const uint4 v = *reinterpret_cast<const uint4*>(vh + (size_t)ia[c] * 256);
      const float wc_ = wa[c];
      acc[0] = fmaf(wc_, lo2f(v.x), acc[0]);
      acc[1] = fmaf(wc_, hi2f(v.x), acc[1]);
      acc[2] = fmaf(wc_, lo2f(v.y), acc[2]);
      acc[3] = fmaf(wc_, hi2f(v.y), acc[3]);
      acc[4] = fmaf(wc_, lo2f(v.z), acc[4]);
      acc[5] = fmaf(wc_, hi2f(v.z), acc[5]);
      acc[6] = fmaf(wc_, lo2f(v.w), acc[6]);
      acc[7] = fmaf(wc_, hi2f(v.w), acc[7]);
    }
  }
  uint4 o;
  o.x = (unsigned)f2b(acc[0]) | ((unsigned)f2b(acc[1]) << 16);
  o.y = (unsigned)f2b(acc[2]) | ((unsigned)f2b(acc[3]) << 16);
  o.z = (unsigned)f2b(acc[4]) | ((unsigned)f2b(acc[5]) << 16);
  o.w = (unsigned)f2b(acc[6]) | ((unsigned)f2b(acc[7]) << 16);
  *reinterpret_cast<uint4*>(acc_out + (size_t)row * 512 + s * 256 + h * 32 + dg * 8) = o;
}

// -------------------------------- launcher -------------------------------------
extern "C" void kernel_launch(void* const* d_in, const int* in_sizes, int n_in,
                              void* d_out, int out_size, void* d_ws, size_t ws_size,
                              hipStream_t stream) {
  const float* query0 = (const float*)d_in[0];
  const float* query1 = (const float*)d_in[1];
  const float* feat0  = (const float*)d_in[2];
  const float* feat1  = (const float*)d_in[3];
  const float* refp   = (const float*)d_in[4];
  const float* W_off  = (const float*)d_in[5];
  const float* W_attn = (const float*)d_in[7];
  const float* W_val  = (const float*)d_in[9];
  const float* b_val  = (const float*)d_in[10];
  const float* W_out  = (const float*)d_in[11];
  const float* b_out  = (const float*)d_in[12];
  const float* W_agg  = (const float*)d_in[13];
  const float* b_agg  = (const float*)d_in[14];
  float* out = (float*)d_out;

  char* p = (char*)d_ws;
  const size_t SZ = (size_t)MQ_ * 256;                 // elems per (MQ,256)
  unsigned short* qb    = (unsigned short*)p; p += 2 * SZ * 2;   // qb0, qb1
  unsigned short* fb    = (unsigned short*)p; p += 2 * SZ * 2;   // fb0, fb1 -> acc overlay
  unsigned short* valb  = (unsigned short*)p; p += 2 * SZ * 2;
  unsigned short* oab   = (unsigned short*)p; p += (size_t)2 * MQ_ * 384 * 2;
  unsigned short* Wvalb = (unsigned short*)p; p += 256 * 256 * 2;
  unsigned short* Wcatb = (unsigned short*)p; p += 384 * 256 * 2;
  unsigned short* Wfinb = (unsigned short*)p; p += 256 * 512 * 2;
  float* bcat = (float*)p; p += 384 * 4;
  float* bfin = (float*)p; p += 256 * 4;
  unsigned short* acc = fb;                            // overlay: (MQ,512) bf16

  const int n4 = MQ_ * 256 / 4;
  cvt_bf16_4<<<dim3(1024, 4), 256, 0, stream>>>(query0, query1, feat0, feat1, qb, n4);
  cvt_bf16<<<64, 256, 0, stream>>>(W_val,  Wvalb, 256*256/4);
  cvt_bf16<<<64, 256, 0, stream>>>(W_off,  Wcatb, 256*256/4);
  cvt_bf16<<<32, 256, 0, stream>>>(W_attn, Wcatb + 256*256, 128*256/4);
  prep_bcat<<<1, 384, 0, stream>>>((const float*)d_in[6], (const float*)d_in[8], bcat);
  compute_wc  <<<dim3(256, 2), 256, 0, stream>>>(W_agg, W_out, Wfinb);
  compute_bfin<<<1, 256, 0, stream>>>(W_agg, b_agg, b_out, bfin);

  // value projections, both streams in one dispatch (blockIdx.z)
  gemm_bf16_nt<true><<<dim3(170, 2, 2), 256, 0, stream>>>(
      fb, Wvalb, b_val, valb, MQ_, 256, 256, SZ, SZ);
  // fused offset+attn projections, both streams
  gemm_bf16_nt<true><<<dim3(170, 3, 2), 256, 0, stream>>>(
      qb, Wcatb, bcat, oab, MQ_, 384, 256, SZ, (size_t)MQ_ * 384);
  // sampling, both streams, acc interleaved (MQ,512)
  deform_sample2<<<dim3(MQ_ / 8, 2), 256, 0, stream>>>(valb, oab, refp, acc);
  // final fused out+agg projection: K=512
  gemm_bf16_nt<false><<<dim3(170, 2, 1), 256, 0, stream>>>(
      acc, Wfinb, bfin, out, MQ_, 256, 512, 0, 0);
}

// Round 4
// 184.183 us; speedup vs baseline: 4.8699x; 1.0606x over previous
//
#include <hip/hip_runtime.h>
#include <math.h>

#define N_   4
#define LQ_  5440
#define MQ_  (N_*LQ_)   // 21760 rows; /8 = 2720 blocks; /128 = 170 tiles

typedef _Float16 f16;
typedef __attribute__((ext_vector_type(8))) _Float16 f16x8;
typedef __attribute__((ext_vector_type(4))) float     f32x4;

__device__ __forceinline__ unsigned short f2h(float f) {
  union { f16 h; unsigned short u; } v; v.h = (f16)f; return v.u;
}
__device__ __forceinline__ float h2f(unsigned short u) {
  union { unsigned short u; f16 h; } v; v.u = u; return (float)v.h;
}

#define GLD16(gp, lp) __builtin_amdgcn_global_load_lds( \
    (const __attribute__((address_space(1))) void*)(gp), \
    (__attribute__((address_space(3))) void*)(lp), 16, 0, 0)

// -------- fp32 -> fp16 convert, 4 tensors (q0,q1,f0,f1) in one dispatch --------
__global__ __launch_bounds__(256)
void cvt_f16_4(const float* __restrict__ p0, const float* __restrict__ p1,
               const float* __restrict__ p2, const float* __restrict__ p3,
               unsigned short* __restrict__ out, int n4) {
  const float* srcs[4] = {p0, p1, p2, p3};
  const float* in = srcs[blockIdx.y];
  unsigned short* o = out + (size_t)blockIdx.y * n4 * 4;
  int i = blockIdx.x * blockDim.x + threadIdx.x;
  const int stride = gridDim.x * blockDim.x;
  for (; i < n4; i += stride) {
    float4 v = reinterpret_cast<const float4*>(in)[i];
    ushort4 r;
    r.x = f2h(v.x); r.y = f2h(v.y); r.z = f2h(v.z); r.w = f2h(v.w);
    reinterpret_cast<ushort4*>(o)[i] = r;
  }
}

// -------- all weight prep in ONE dispatch (grid = 675 blocks x 256) ------------
// b<64: W_val cvt | b<128: W_off cvt | b<160: W_attn cvt | b<672: Wfin matmul |
// b==672: bfin | b==673/674: bcat
__global__ __launch_bounds__(256)
void prep(const float* __restrict__ W_val, const float* __restrict__ W_off,
          const float* __restrict__ W_attn, const float* __restrict__ W_agg,
          const float* __restrict__ W_out, const float* __restrict__ b_off,
          const float* __restrict__ b_attn, const float* __restrict__ b_agg,
          const float* __restrict__ b_out,
          unsigned short* __restrict__ Wvalh, unsigned short* __restrict__ Wcath,
          unsigned short* __restrict__ Wfinh, float* __restrict__ bcat,
          float* __restrict__ bfin) {
  __shared__ float wrow[256];
  const int b = blockIdx.x, t = threadIdx.x;
  if (b < 160) {
    const float* src; unsigned short* dst; int i;
    if (b < 64)       { src = W_val;  dst = Wvalh;          i = b * 256 + t; }
    else if (b < 128) { src = W_off;  dst = Wcath;          i = (b - 64) * 256 + t; }
    else              { src = W_attn; dst = Wcath + 65536;  i = (b - 128) * 256 + t; }
    float4 v = reinterpret_cast<const float4*>(src)[i];
    ushort4 r;
    r.x = f2h(v.x); r.y = f2h(v.y); r.z = f2h(v.z); r.w = f2h(v.w);
    reinterpret_cast<ushort4*>(dst)[i] = r;
  } else if (b < 672) {
    const int idx = b - 160, j = idx & 255, s = idx >> 8;
    wrow[t] = W_agg[(size_t)j * 512 + s * 256 + t];
    __syncthreads();
    float a = 0.f;
    for (int i = 0; i < 256; ++i) a = fmaf(wrow[i], W_out[(size_t)i * 256 + t], a);
    Wfinh[(size_t)j * 512 + s * 256 + t] = f2h(a);
  } else if (b == 672) {
    float s = b_agg[t];
    for (int i = 0; i < 256; ++i)
      s = fmaf(W_agg[(size_t)t * 512 + i] + W_agg[(size_t)t * 512 + 256 + i], b_out[i], s);
    bfin[t] = s;
  } else if (b == 673) {
    bcat[t] = b_off[t];
  } else {
    if (t < 128) bcat[256 + t] = b_attn[t];
  }
}

// -------- f16 MFMA GEMM tile core: C[128,128] = A @ W^T + bias -----------------
// 128x128 tile, BK=64, 256 threads, global_load_lds(16B), XOR chunk swizzle.
template<bool OUT32>
__device__ __forceinline__
void gemm_tile_f16(const unsigned short* __restrict__ A,
                   const unsigned short* __restrict__ W,
                   const float* __restrict__ bias, void* __restrict__ Cv,
                   int NC, int K, int row0, int col0,
                   unsigned short* As, unsigned short* Ws) {
  const int t    = threadIdx.x;
  const int lane = t & 63;
  const int wv   = t >> 6;
  const int wr   = wv >> 1, wc = wv & 1;
  const int srow   = t >> 3;
  const int schunk = t & 7;
  const int wbase  = wv * 512;

  f32x4 acc[4][4] = {};

  for (int k0 = 0; k0 < K; k0 += 64) {
    __syncthreads();
    #pragma unroll
    for (int i = 0; i < 4; ++i) {
      const int row = i * 32 + srow;
      const int ch  = schunk ^ (row & 7);
      GLD16(A + (size_t)(row0 + row) * K + k0 + ch * 8, &As[i * 2048 + wbase]);
      GLD16(W + (size_t)(col0 + row) * K + k0 + ch * 8, &Ws[i * 2048 + wbase]);
    }
    __syncthreads();

    f16x8 af[4][2], bfr[4][2];
    #pragma unroll
    for (int f = 0; f < 4; ++f)
      #pragma unroll
      for (int kk = 0; kk < 2; ++kk) {
        const int ra = wr * 64 + f * 16 + (lane & 15);
        const int ca = (kk * 4 + (lane >> 4)) ^ (ra & 7);
        af[f][kk] = *(const f16x8*)&As[ra * 64 + ca * 8];
        const int rb = wc * 64 + f * 16 + (lane & 15);
        const int cb = (kk * 4 + (lane >> 4)) ^ (rb & 7);
        bfr[f][kk] = *(const f16x8*)&Ws[rb * 64 + cb * 8];
      }
    #pragma unroll
    for (int kk = 0; kk < 2; ++kk)
      #pragma unroll
      for (int fm = 0; fm < 4; ++fm)
        #pragma unroll
        for (int fn = 0; fn < 4; ++fn)
          acc[fm][fn] = __builtin_amdgcn_mfma_f32_16x16x32_f16(
              af[fm][kk], bfr[fn][kk], acc[fm][fn], 0, 0, 0);
  }

  // D: col = lane&15, row = (lane>>4)*4 + r
  #pragma unroll
  for (int fm = 0; fm < 4; ++fm) {
    const int m = row0 + wr * 64 + fm * 16 + (lane >> 4) * 4;
    #pragma unroll
    for (int fn = 0; fn < 4; ++fn) {
      const int c = col0 + wc * 64 + fn * 16 + (lane & 15);
      const float bv = bias ? bias[c] : 0.f;
      #pragma unroll
      for (int r = 0; r < 4; ++r) {
        const float v = acc[fm][fn][r] + bv;
        if (OUT32) ((float*)Cv)[(size_t)(m + r) * NC + c] = v;
        else       ((unsigned short*)Cv)[(size_t)(m + r) * NC + c] = f2h(v);
      }
    }
  }
}

// -------- stage-1 GEMMs: val (y<2) + off/attn (y>=2), both streams (z) ---------
__global__ __launch_bounds__(256)
void gemm_stage1(const unsigned short* __restrict__ qb,
                 const unsigned short* __restrict__ fb,
                 const unsigned short* __restrict__ Wvalh,
                 const unsigned short* __restrict__ Wcath,
                 const float* __restrict__ b_val, const float* __restrict__ bcat,
                 unsigned short* __restrict__ valb, unsigned short* __restrict__ oab) {
  __shared__ __align__(16) unsigned short As[128 * 64];
  __shared__ __align__(16) unsigned short Ws[128 * 64];
  const int y = blockIdx.y, z = blockIdx.z;
  const size_t SZ = (size_t)MQ_ * 256;
  const unsigned short *A, *W; const float* bias; unsigned short* C; int NC, col0;
  if (y < 2) { A = fb + z * SZ; W = Wvalh; bias = b_val; C = valb + z * SZ;            NC = 256; col0 = y * 128; }
  else       { A = qb + z * SZ; W = Wcath; bias = bcat;  C = oab + (size_t)z * MQ_ * 384; NC = 384; col0 = (y - 2) * 128; }
  gemm_tile_f16<false>(A, W, bias, C, NC, 256, blockIdx.x * 128, col0, As, Ws);
}

// -------- final GEMM: out = acc(MQ,512) @ Wfin^T + bfin, fp32 out --------------
__global__ __launch_bounds__(256)
void gemm_final(const unsigned short* __restrict__ acc,
                const unsigned short* __restrict__ Wfinh,
                const float* __restrict__ bfin, float* __restrict__ out) {
  __shared__ __align__(16) unsigned short As[128 * 64];
  __shared__ __align__(16) unsigned short Ws[128 * 64];
  gemm_tile_f16<true>(acc, Wfinh, bfin, out, 256, 512,
                      blockIdx.x * 128, blockIdx.y * 128, As, Ws);
}

// ------------------------- deformable sampling (both streams) ------------------
// grid (MQ/8, 2); block 256 = 8 queries x 32 threads.
// Phase 1: 32 threads x 4 points; softmax via 16-lane shfl; pack per point ONE
//   uint4 {idx01, idx23, w01(f16), w23(f16)} at lds[q][j][h^(j&7)] (ds_write_b128,
//   conflict-free, 16 KB total).
// Phase 2: thread=(q, h=tq>>2, dg=tq&3): per j one ds_read_b128 + 4 x f16x8 gather.
__global__ __launch_bounds__(256)
void deform_sample3(const unsigned short* __restrict__ vals,  // (2,N,LQ,256) f16
                    const unsigned short* __restrict__ oa,    // (2,MQ,384) f16
                    const float* __restrict__ refp,           // (N,LQ,4,2) f32
                    unsigned short* __restrict__ acc_out) {   // (MQ,512) f16
  const int s  = blockIdx.y;
  const int t  = threadIdx.x;
  const int q  = t >> 5, tq = t & 31;
  const int row = blockIdx.x * 8 + q;
  const int n  = row / LQ_;
  __shared__ uint4 lds[8][16][8];   // 16 KB

  const unsigned short* oar = oa + ((size_t)s * MQ_ + row) * 384;
  const int LSa[4] = {64, 32, 16, 8};
  const int LBa[4] = {0, 4096, 5120, 5376};
  #pragma unroll
  for (int k = 0; k < 4; ++k) {
    const int pp = tq + 32 * k;               // h=pp>>4, l=(pp>>2)&3, p=pp&3
    const int l  = (pp >> 2) & 3;
    const int   Wn = LSa[l];
    const float Wf = (float)Wn;
    const float ox = h2f(oar[pp * 2]);
    const float oy = h2f(oar[pp * 2 + 1]);
    const float rx = refp[((size_t)row * 4 + l) * 2 + 0];
    const float ry = refp[((size_t)row * 4 + l) * 2 + 1];
    const float x = fmaf(rx, Wf, ox) - 0.5f;
    const float y = fmaf(ry, Wf, oy) - 0.5f;
    const float x0f = floorf(x), y0f = floorf(y);
    const int   x0 = (int)x0f,   y0 = (int)y0f;
    const float lx = x - x0f,    ly = y - y0f;
    // softmax over this head's 16 logits (lanes grouped by 16)
    float logit = h2f(oar[256 + pp]);
    float mx = logit;
    #pragma unroll
    for (int dd = 1; dd < 16; dd <<= 1) mx = fmaxf(mx, __shfl_xor(mx, dd));
    const float e = __expf(logit - mx);
    float se = e;
    #pragma unroll
    for (int dd = 1; dd < 16; dd <<= 1) se += __shfl_xor(se, dd);
    const float aw = e / se;
    const int   xs[2] = {x0, x0 + 1}, ys[2] = {y0, y0 + 1};
    const float wx[2] = {1.f - lx, lx}, wy[2] = {1.f - ly, ly};
    unsigned ia[4]; unsigned short wa[4];
    #pragma unroll
    for (int cy = 0; cy < 2; ++cy)
      #pragma unroll
      for (int cx = 0; cx < 2; ++cx) {
        const int xi = xs[cx], yi = ys[cy];
        const bool v = (xi >= 0) && (xi < Wn) && (yi >= 0) && (yi < Wn);
        const int xc = min(max(xi, 0), Wn - 1), yc = min(max(yi, 0), Wn - 1);
        ia[cy * 2 + cx] = (unsigned)(LBa[l] + yc * Wn + xc);
        wa[cy * 2 + cx] = f2h(v ? wx[cx] * wy[cy] * aw : 0.f);
      }
    uint4 rec;
    rec.x = ia[0] | (ia[1] << 16);
    rec.y = ia[2] | (ia[3] << 16);
    rec.z = (unsigned)wa[0] | ((unsigned)wa[1] << 16);
    rec.w = (unsigned)wa[2] | ((unsigned)wa[3] << 16);
    lds[q][pp & 15][(pp >> 4) ^ (pp & 7)] = rec;
  }
  __syncthreads();

  const int h = tq >> 2, dg = tq & 3;
  const f16* vh = (const f16*)vals + ((size_t)s * N_ + n) * LQ_ * 256 + h * 32 + dg * 8;
  float acc[8] = {};
  #pragma unroll
  for (int j = 0; j < 16; ++j) {
    const uint4 m = lds[q][j][h ^ (j & 7)];
    const unsigned idx[4] = { m.x & 0xFFFFu, m.x >> 16, m.y & 0xFFFFu, m.y >> 16 };
    const float    wf[4] = { h2f((unsigned short)(m.z & 0xFFFFu)),
                             h2f((unsigned short)(m.z >> 16)),
                             h2f((unsigned short)(m.w & 0xFFFFu)),
                             h2f((unsigned short)(m.w >> 16)) };
    #pragma unroll
    for (int c = 0; c < 4; ++c) {
      const f16x8 v = *reinterpret_cast<const f16x8*>(vh + ((size_t)idx[c] << 8));
      #pragma unroll
      for (int e = 0; e < 8; ++e)
        acc[e] = fmaf((float)v[e], wf[c], acc[e]);
    }
  }
  uint4 o;
  o.x = (unsigned)f2h(acc[0]) | ((unsigned)f2h(acc[1]) << 16);
  o.y = (unsigned)f2h(acc[2]) | ((unsigned)f2h(acc[3]) << 16);
  o.z = (unsigned)f2h(acc[4]) | ((unsigned)f2h(acc[5]) << 16);
  o.w = (unsigned)f2h(acc[6]) | ((unsigned)f2h(acc[7]) << 16);
  *reinterpret_cast<uint4*>(acc_out + (size_t)row * 512 + s * 256 + h * 32 + dg * 8) = o;
}

// -------------------------------- launcher -------------------------------------
extern "C" void kernel_launch(void* const* d_in, const int* in_sizes, int n_in,
                              void* d_out, int out_size, void* d_ws, size_t ws_size,
                              hipStream_t stream) {
  const float* query0 = (const float*)d_in[0];
  const float* query1 = (const float*)d_in[1];
  const float* feat0  = (const float*)d_in[2];
  const float* feat1  = (const float*)d_in[3];
  const float* refp   = (const float*)d_in[4];
  const float* W_off  = (const float*)d_in[5];
  const float* b_off  = (const float*)d_in[6];
  const float* W_attn = (const float*)d_in[7];
  const float* b_attn = (const float*)d_in[8];
  const float* W_val  = (const float*)d_in[9];
  const float* b_val  = (const float*)d_in[10];
  const float* W_out  = (const float*)d_in[11];
  const float* b_out  = (const float*)d_in[12];
  const float* W_agg  = (const float*)d_in[13];
  const float* b_agg  = (const float*)d_in[14];
  float* out = (float*)d_out;

  char* p = (char*)d_ws;
  const size_t SZ = (size_t)MQ_ * 256;                 // elems per (MQ,256)
  unsigned short* qb    = (unsigned short*)p; p += 2 * SZ * 2;   // q0,q1 f16
  unsigned short* fb    = (unsigned short*)p; p += 2 * SZ * 2;   // f0,f1 -> acc overlay
  unsigned short* valb  = (unsigned short*)p; p += 2 * SZ * 2;
  unsigned short* oab   = (unsigned short*)p; p += (size_t)2 * MQ_ * 384 * 2;
  unsigned short* Wvalh = (unsigned short*)p; p += 256 * 256 * 2;
  unsigned short* Wcath = (unsigned short*)p; p += 384 * 256 * 2;
  unsigned short* Wfinh = (unsigned short*)p; p += 256 * 512 * 2;
  float* bcat = (float*)p; p += 384 * 4;
  float* bfin = (float*)p; p += 256 * 4;
  unsigned short* acc = fb;                            // overlay: (MQ,512) f16

  const int n4 = MQ_ * 256 / 4;
  cvt_f16_4<<<dim3(1024, 4), 256, 0, stream>>>(query0, query1, feat0, feat1, qb, n4);
  prep<<<675, 256, 0, stream>>>(W_val, W_off, W_attn, W_agg, W_out, b_off, b_attn,
                                b_agg, b_out, Wvalh, Wcath, Wfinh, bcat, bfin);
  // val (y<2) + off/attn (y>=2) projections, both streams, ONE dispatch
  gemm_stage1<<<dim3(170, 5, 2), 256, 0, stream>>>(qb, fb, Wvalh, Wcath,
                                                   b_val, bcat, valb, oab);
  // sampling, both streams, acc interleaved (MQ,512)
  deform_sample3<<<dim3(MQ_ / 8, 2), 256, 0, stream>>>(valb, oab, refp, acc);
  // final fused out+agg projection: K=512
  gemm_final<<<dim3(170, 2), 256, 0, stream>>>(acc, Wfinh, bfin, out);
}

// Round 5
// 168.562 us; speedup vs baseline: 5.3212x; 1.0927x over previous
//
#include <hip/hip_runtime.h>
#include <math.h>

#define N_   4
#define LQ_  5440
#define MQ_  (N_*LQ_)   // 21760 rows; /8 = 2720 blocks; /128 = 170 tiles

typedef _Float16 f16;
typedef __attribute__((ext_vector_type(2))) _Float16 f16x2;
typedef __attribute__((ext_vector_type(8))) _Float16 f16x8;
typedef __attribute__((ext_vector_type(4))) float     f32x4;

__device__ __forceinline__ unsigned short f2h(float f) {
  union { f16 h; unsigned short u; } v; v.h = (f16)f; return v.u;
}
__device__ __forceinline__ float h2f(unsigned u) {   // low 16 bits
  union { unsigned short u; f16 h; } v; v.u = (unsigned short)u; return (float)v.h;
}
__device__ __forceinline__ f16x2 u2h2(unsigned u) {
  union { unsigned u; f16x2 h; } v; v.u = u; return v.h;
}

#define GLD16(gp, lp) __builtin_amdgcn_global_load_lds( \
    (const __attribute__((address_space(1))) void*)(gp), \
    (__attribute__((address_space(3))) void*)(lp), 16, 0, 0)

// -------- all weight prep in ONE dispatch (grid = 675 blocks x 256) ------------
// b<64: W_val cvt | b<128: W_off cvt | b<160: W_attn cvt | b<672: Wfin matmul |
// b==672: bfin | b==673/674: bcat
__global__ __launch_bounds__(256)
void prep(const float* __restrict__ W_val, const float* __restrict__ W_off,
          const float* __restrict__ W_attn, const float* __restrict__ W_agg,
          const float* __restrict__ W_out, const float* __restrict__ b_off,
          const float* __restrict__ b_attn, const float* __restrict__ b_agg,
          const float* __restrict__ b_out,
          unsigned short* __restrict__ Wvalh, unsigned short* __restrict__ Wcath,
          unsigned short* __restrict__ Wfinh, float* __restrict__ bcat,
          float* __restrict__ bfin) {
  __shared__ float wrow[256];
  const int b = blockIdx.x, t = threadIdx.x;
  if (b < 160) {
    const float* src; unsigned short* dst; int i;
    if (b < 64)       { src = W_val;  dst = Wvalh;          i = b * 256 + t; }
    else if (b < 128) { src = W_off;  dst = Wcath;          i = (b - 64) * 256 + t; }
    else              { src = W_attn; dst = Wcath + 65536;  i = (b - 128) * 256 + t; }
    float4 v = reinterpret_cast<const float4*>(src)[i];
    ushort4 r;
    r.x = f2h(v.x); r.y = f2h(v.y); r.z = f2h(v.z); r.w = f2h(v.w);
    reinterpret_cast<ushort4*>(dst)[i] = r;
  } else if (b < 672) {
    const int idx = b - 160, j = idx & 255, s = idx >> 8;
    wrow[t] = W_agg[(size_t)j * 512 + s * 256 + t];
    __syncthreads();
    float a = 0.f;
    for (int i = 0; i < 256; ++i) a = fmaf(wrow[i], W_out[(size_t)i * 256 + t], a);
    Wfinh[(size_t)j * 512 + s * 256 + t] = f2h(a);
  } else if (b == 672) {
    float s = b_agg[t];
    for (int i = 0; i < 256; ++i)
      s = fmaf(W_agg[(size_t)t * 512 + i] + W_agg[(size_t)t * 512 + 256 + i], b_out[i], s);
    bfin[t] = s;
  } else if (b == 673) {
    bcat[t] = b_off[t];
  } else {
    if (t < 128) bcat[256 + t] = b_attn[t];
  }
}

// -------- stage-1 GEMM with fused fp32->f16 A-staging --------------------------
// C[128,128] = cvt_f16(A_fp32) @ W_f16^T + bias. 128x128 tile, BK=64, 256 thr.
// A: reg-staged (float4 x2 -> cvt -> swizzled ds_write_b128); W: global_load_lds.
__global__ __launch_bounds__(256)
void gemm_stage1(const float* __restrict__ q0, const float* __restrict__ q1,
                 const float* __restrict__ f0, const float* __restrict__ f1,
                 const unsigned short* __restrict__ Wvalh,
                 const unsigned short* __restrict__ Wcath,
                 const float* __restrict__ b_val, const float* __restrict__ bcat,
                 unsigned short* __restrict__ valb, unsigned short* __restrict__ oab) {
  __shared__ __align__(16) unsigned short As[128 * 64];
  __shared__ __align__(16) unsigned short Ws[128 * 64];
  const int y = blockIdx.y, z = blockIdx.z;
  const size_t SZ = (size_t)MQ_ * 256;
  const float* A; const unsigned short* W; const float* bias;
  unsigned short* C; int NC, col0;
  if (y < 2) { A = z ? f1 : f0; W = Wvalh; bias = b_val; C = valb + z * SZ;              NC = 256; col0 = y * 128; }
  else       { A = z ? q1 : q0; W = Wcath; bias = bcat;  C = oab + (size_t)z * MQ_ * 384; NC = 384; col0 = (y - 2) * 128; }

  const int t    = threadIdx.x;
  const int lane = t & 63;
  const int wv   = t >> 6;
  const int wr   = wv >> 1, wc = wv & 1;
  const int row0 = blockIdx.x * 128;
  const int srow = t >> 3, schunk = t & 7;
  const int wbase = wv * 512;

  f32x4 acc[4][4] = {};

  for (int k0 = 0; k0 < 256; k0 += 64) {
    __syncthreads();
    #pragma unroll
    for (int i = 0; i < 4; ++i) {                  // W: direct-to-LDS, pre-swizzled src
      const int row = i * 32 + srow;
      const int ch  = schunk ^ (row & 7);
      GLD16(W + (size_t)(col0 + row) * 256 + k0 + ch * 8, &Ws[i * 2048 + wbase]);
    }
    #pragma unroll
    for (int i = 0; i < 4; ++i) {                  // A: fp32 reg-stage + cvt
      const int row = i * 32 + srow;
      const float* src = A + (size_t)(row0 + row) * 256 + k0 + schunk * 8;
      const float4 a0 = *reinterpret_cast<const float4*>(src);
      const float4 a1 = *reinterpret_cast<const float4*>(src + 4);
      f16x8 hv;
      hv[0] = (f16)a0.x; hv[1] = (f16)a0.y; hv[2] = (f16)a0.z; hv[3] = (f16)a0.w;
      hv[4] = (f16)a1.x; hv[5] = (f16)a1.y; hv[6] = (f16)a1.z; hv[7] = (f16)a1.w;
      const int ch = schunk ^ (row & 7);
      *reinterpret_cast<f16x8*>(&As[row * 64 + ch * 8]) = hv;
    }
    __syncthreads();

    f16x8 af[4][2], bfr[4][2];
    #pragma unroll
    for (int f = 0; f < 4; ++f)
      #pragma unroll
      for (int kk = 0; kk < 2; ++kk) {
        const int ra = wr * 64 + f * 16 + (lane & 15);
        const int ca = (kk * 4 + (lane >> 4)) ^ (ra & 7);
        af[f][kk] = *(const f16x8*)&As[ra * 64 + ca * 8];
        const int rb = wc * 64 + f * 16 + (lane & 15);
        const int cb = (kk * 4 + (lane >> 4)) ^ (rb & 7);
        bfr[f][kk] = *(const f16x8*)&Ws[rb * 64 + cb * 8];
      }
    #pragma unroll
    for (int kk = 0; kk < 2; ++kk)
      #pragma unroll
      for (int fm = 0; fm < 4; ++fm)
        #pragma unroll
        for (int fn = 0; fn < 4; ++fn)
          acc[fm][fn] = __builtin_amdgcn_mfma_f32_16x16x32_f16(
              af[fm][kk], bfr[fn][kk], acc[fm][fn], 0, 0, 0);
  }

  #pragma unroll
  for (int fm = 0; fm < 4; ++fm) {
    const int m = row0 + wr * 64 + fm * 16 + (lane >> 4) * 4;
    #pragma unroll
    for (int fn = 0; fn < 4; ++fn) {
      const int c = col0 + wc * 64 + fn * 16 + (lane & 15);
      const float bv = bias[c];
      #pragma unroll
      for (int r = 0; r < 4; ++r)
        C[(size_t)(m + r) * NC + c] = f2h(acc[fm][fn][r] + bv);
    }
  }
}

// -------- final GEMM: out = acc(MQ,512 f16) @ Wfin^T + bfin, fp32 out ----------
__global__ __launch_bounds__(256)
void gemm_final(const unsigned short* __restrict__ A,
                const unsigned short* __restrict__ W,
                const float* __restrict__ bias, float* __restrict__ out) {
  __shared__ __align__(16) unsigned short As[128 * 64];
  __shared__ __align__(16) unsigned short Ws[128 * 64];
  const int t    = threadIdx.x;
  const int lane = t & 63;
  const int wv   = t >> 6;
  const int wr   = wv >> 1, wc = wv & 1;
  const int row0 = blockIdx.x * 128, col0 = blockIdx.y * 128;
  const int srow = t >> 3, schunk = t & 7;
  const int wbase = wv * 512;

  f32x4 acc[4][4] = {};

  for (int k0 = 0; k0 < 512; k0 += 64) {
    __syncthreads();
    #pragma unroll
    for (int i = 0; i < 4; ++i) {
      const int row = i * 32 + srow;
      const int ch  = schunk ^ (row & 7);
      GLD16(A + (size_t)(row0 + row) * 512 + k0 + ch * 8, &As[i * 2048 + wbase]);
      GLD16(W + (size_t)(col0 + row) * 512 + k0 + ch * 8, &Ws[i * 2048 + wbase]);
    }
    __syncthreads();

    f16x8 af[4][2], bfr[4][2];
    #pragma unroll
    for (int f = 0; f < 4; ++f)
      #pragma unroll
      for (int kk = 0; kk < 2; ++kk) {
        const int ra = wr * 64 + f * 16 + (lane & 15);
        const int ca = (kk * 4 + (lane >> 4)) ^ (ra & 7);
        af[f][kk] = *(const f16x8*)&As[ra * 64 + ca * 8];
        const int rb = wc * 64 + f * 16 + (lane & 15);
        const int cb = (kk * 4 + (lane >> 4)) ^ (rb & 7);
        bfr[f][kk] = *(const f16x8*)&Ws[rb * 64 + cb * 8];
      }
    #pragma unroll
    for (int kk = 0; kk < 2; ++kk)
      #pragma unroll
      for (int fm = 0; fm < 4; ++fm)
        #pragma unroll
        for (int fn = 0; fn < 4; ++fn)
          acc[fm][fn] = __builtin_amdgcn_mfma_f32_16x16x32_f16(
              af[fm][kk], bfr[fn][kk], acc[fm][fn], 0, 0, 0);
  }

  #pragma unroll
  for (int fm = 0; fm < 4; ++fm) {
    const int m = row0 + wr * 64 + fm * 16 + (lane >> 4) * 4;
    #pragma unroll
    for (int fn = 0; fn < 4; ++fn) {
      const int c = col0 + wc * 64 + fn * 16 + (lane & 15);
      const float bv = bias[c];
      #pragma unroll
      for (int r = 0; r < 4; ++r)
        out[(size_t)(m + r) * 256 + c] = acc[fm][fn][r] + bv;
    }
  }
}

// ------------------------- deformable sampling (both streams) ------------------
// grid (MQ/8, 2); block 256 = 8 queries x 32 threads.
// Phase 1: thread tq owns head h=tq>>2, level l=tq&3, points p=0..3:
//   ONE uint4 offset load + uint2 logits; softmax via 2 shfl_xor; pack per point
//   uint4 {idx01, idx23, w01(f16), w23(f16)} at lds[q][j][h^(j&7)].
// Phase 2: thread=(q, h=tq>>2, dg=tq&3): per corner one 32-bit-voffset f16x8
//   gather + 4 v_pk_fma_f16 into per-level f16x2[4] acc; f32 promote per level.
__global__ __launch_bounds__(256)
void deform_sample4(const unsigned short* __restrict__ vals,  // (2,N,LQ,256) f16
                    const unsigned short* __restrict__ oa,    // (2,MQ,384) f16
                    const float* __restrict__ refp,           // (N,LQ,4,2) f32
                    unsigned short* __restrict__ acc_out) {   // (MQ,512) f16
  const int s  = blockIdx.y;
  const int t  = threadIdx.x;
  const int q  = t >> 5, tq = t & 31;
  const int row = blockIdx.x * 8 + q;
  const int n  = row / LQ_;
  const int h  = tq >> 2;
  __shared__ uint4 lds[8][16][8];   // 16 KB

  const unsigned short* oar = oa + ((size_t)s * MQ_ + row) * 384;
  {
    const int   l  = tq & 3;
    const int   Wn = 64 >> l;
    const float Wf = (float)Wn;
    const int   lb = (int)(((0xAD200u >> (5 * l)) & 31u) << 8);  // {0,4096,5120,5376}
    const uint4 ov = *reinterpret_cast<const uint4*>(oar + (size_t)tq * 8);
    const uint2 lv = *reinterpret_cast<const uint2*>(oar + 256 + (size_t)tq * 4);
    const float2 rxy = *reinterpret_cast<const float2*>(refp + (size_t)row * 8 + l * 2);
    // softmax over this head's 16 logits: 4 per lane, 4 lanes (tq>>2 groups)
    float lg[4] = { h2f(lv.x), h2f(lv.x >> 16), h2f(lv.y), h2f(lv.y >> 16) };
    float mx = fmaxf(fmaxf(lg[0], lg[1]), fmaxf(lg[2], lg[3]));
    mx = fmaxf(mx, __shfl_xor(mx, 1));
    mx = fmaxf(mx, __shfl_xor(mx, 2));
    float e[4], se;
    #pragma unroll
    for (int k = 0; k < 4; ++k) e[k] = __expf(lg[k] - mx);
    se = (e[0] + e[1]) + (e[2] + e[3]);
    se += __shfl_xor(se, 1);
    se += __shfl_xor(se, 2);
    const float inv = 1.f / se;
    const unsigned od[4] = { ov.x, ov.y, ov.z, ov.w };
    #pragma unroll
    for (int k = 0; k < 4; ++k) {
      const float ox = h2f(od[k]), oy = h2f(od[k] >> 16);
      const float x = fmaf(rxy.x, Wf, ox) - 0.5f;
      const float y = fmaf(rxy.y, Wf, oy) - 0.5f;
      const float x0f = floorf(x), y0f = floorf(y);
      const int   x0 = (int)x0f,   y0 = (int)y0f;
      const float lx = x - x0f,    ly = y - y0f;
      const float aw = e[k] * inv;
      const int   xs[2] = {x0, x0 + 1}, ys[2] = {y0, y0 + 1};
      const float wx[2] = {1.f - lx, lx}, wy[2] = {1.f - ly, ly};
      unsigned ia[4]; unsigned short wa[4];
      #pragma unroll
      for (int cy = 0; cy < 2; ++cy)
        #pragma unroll
        for (int cx = 0; cx < 2; ++cx) {
          const int xi = xs[cx], yi = ys[cy];
          const bool v = (xi >= 0) && (xi < Wn) && (yi >= 0) && (yi < Wn);
          const int xc = min(max(xi, 0), Wn - 1), yc = min(max(yi, 0), Wn - 1);
          ia[cy * 2 + cx] = (unsigned)(lb + yc * Wn + xc);
          wa[cy * 2 + cx] = f2h(v ? wx[cx] * wy[cy] * aw : 0.f);
        }
      uint4 rec;
      rec.x = ia[0] | (ia[1] << 16);
      rec.y = ia[2] | (ia[3] << 16);
      rec.z = (unsigned)wa[0] | ((unsigned)wa[1] << 16);
      rec.w = (unsigned)wa[2] | ((unsigned)wa[3] << 16);
      const int jj = l * 4 + k;
      lds[q][jj][h ^ (jj & 7)] = rec;
    }
  }
  __syncthreads();

  const int dg = tq & 3;
  const char* vb = (const char*)(vals + ((size_t)s * N_ + n) * LQ_ * 256);
  const unsigned hd = (unsigned)((h * 32 + dg * 8) * 2);   // byte offset in value row
  float facc[8] = {};
  #pragma unroll
  for (int l4 = 0; l4 < 4; ++l4) {
    f16x2 a0 = {0, 0}, a1 = {0, 0}, a2 = {0, 0}, a3 = {0, 0};
    #pragma unroll
    for (int p = 0; p < 4; ++p) {
      const int j = l4 * 4 + p;
      const uint4 m = lds[q][j][h ^ (j & 7)];
      const unsigned o0 = ((m.x & 0xffffu) << 9) + hd;
      const unsigned o1 = ((m.x >> 16) << 9) + hd;
      const unsigned o2 = ((m.y & 0xffffu) << 9) + hd;
      const unsigned o3 = ((m.y >> 16) << 9) + hd;
      const f16x8 v0 = *reinterpret_cast<const f16x8*>(vb + o0);
      const f16x8 v1 = *reinterpret_cast<const f16x8*>(vb + o1);
      const f16x8 v2 = *reinterpret_cast<const f16x8*>(vb + o2);
      const f16x8 v3 = *reinterpret_cast<const f16x8*>(vb + o3);
      const f16x2 w0 = u2h2(__builtin_amdgcn_perm(m.z, m.z, 0x01000100u));
      const f16x2 w1 = u2h2(__builtin_amdgcn_perm(m.z, m.z, 0x03020302u));
      const f16x2 w2 = u2h2(__builtin_amdgcn_perm(m.w, m.w, 0x01000100u));
      const f16x2 w3 = u2h2(__builtin_amdgcn_perm(m.w, m.w, 0x03020302u));
      const f16x2* p0 = (const f16x2*)&v0;
      const f16x2* p1 = (const f16x2*)&v1;
      const f16x2* p2 = (const f16x2*)&v2;
      const f16x2* p3 = (const f16x2*)&v3;
      a0 = __builtin_elementwise_fma(p0[0], w0, a0);
      a1 = __builtin_elementwise_fma(p0[1], w0, a1);
      a2 = __builtin_elementwise_fma(p0[2], w0, a2);
      a3 = __builtin_elementwise_fma(p0[3], w0, a3);
      a0 = __builtin_elementwise_fma(p1[0], w1, a0);
      a1 = __builtin_elementwise_fma(p1[1], w1, a1);
      a2 = __builtin_elementwise_fma(p1[2], w1, a2);
      a3 = __builtin_elementwise_fma(p1[3], w1, a3);
      a0 = __builtin_elementwise_fma(p2[0], w2, a0);
      a1 = __builtin_elementwise_fma(p2[1], w2, a1);
      a2 = __builtin_elementwise_fma(p2[2], w2, a2);
      a3 = __builtin_elementwise_fma(p2[3], w2, a3);
      a0 = __builtin_elementwise_fma(p3[0], w3, a0);
      a1 = __builtin_elementwise_fma(p3[1], w3, a1);
      a2 = __builtin_elementwise_fma(p3[2], w3, a2);
      a3 = __builtin_elementwise_fma(p3[3], w3, a3);
    }
    facc[0] += (float)a0[0]; facc[1] += (float)a0[1];
    facc[2] += (float)a1[0]; facc[3] += (float)a1[1];
    facc[4] += (float)a2[0]; facc[5] += (float)a2[1];
    facc[6] += (float)a3[0]; facc[7] += (float)a3[1];
  }
  f16x8 r;
  #pragma unroll
  for (int e2 = 0; e2 < 8; ++e2) r[e2] = (f16)facc[e2];
  *reinterpret_cast<f16x8*>(acc_out + (size_t)row * 512 + s * 256 + h * 32 + dg * 8) = r;
}

// -------------------------------- launcher -------------------------------------
extern "C" void kernel_launch(void* const* d_in, const int* in_sizes, int n_in,
                              void* d_out, int out_size, void* d_ws, size_t ws_size,
                              hipStream_t stream) {
  const float* query0 = (const float*)d_in[0];
  const float* query1 = (const float*)d_in[1];
  const float* feat0  = (const float*)d_in[2];
  const float* feat1  = (const float*)d_in[3];
  const float* refp   = (const float*)d_in[4];
  const float* W_off  = (const float*)d_in[5];
  const float* b_off  = (const float*)d_in[6];
  const float* W_attn = (const float*)d_in[7];
  const float* b_attn = (const float*)d_in[8];
  const float* W_val  = (const float*)d_in[9];
  const float* b_val  = (const float*)d_in[10];
  const float* W_out  = (const float*)d_in[11];
  const float* b_out  = (const float*)d_in[12];
  const float* W_agg  = (const float*)d_in[13];
  const float* b_agg  = (const float*)d_in[14];
  float* out = (float*)d_out;

  char* p = (char*)d_ws;
  const size_t SZ = (size_t)MQ_ * 256;                 // elems per (MQ,256)
  unsigned short* valb  = (unsigned short*)p; p += 2 * SZ * 2;
  unsigned short* oab   = (unsigned short*)p; p += (size_t)2 * MQ_ * 384 * 2;
  unsigned short* accb  = (unsigned short*)p; p += (size_t)MQ_ * 512 * 2;
  unsigned short* Wvalh = (unsigned short*)p; p += 256 * 256 * 2;
  unsigned short* Wcath = (unsigned short*)p; p += 384 * 256 * 2;
  unsigned short* Wfinh = (unsigned short*)p; p += 256 * 512 * 2;
  float* bcat = (float*)p; p += 384 * 4;
  float* bfin = (float*)p; p += 256 * 4;

  prep<<<675, 256, 0, stream>>>(W_val, W_off, W_attn, W_agg, W_out, b_off, b_attn,
                                b_agg, b_out, Wvalh, Wcath, Wfinh, bcat, bfin);
  // val (y<2) + off/attn (y>=2) projections, both streams, fused fp32 cvt
  gemm_stage1<<<dim3(170, 5, 2), 256, 0, stream>>>(query0, query1, feat0, feat1,
                                                   Wvalh, Wcath, b_val, bcat,
                                                   valb, oab);
  // sampling, both streams, acc interleaved (MQ,512)
  deform_sample4<<<dim3(MQ_ / 8, 2), 256, 0, stream>>>(valb, oab, refp, accb);
  // final fused out+agg projection: K=512
  gemm_final<<<dim3(170, 2), 256, 0, stream>>>(accb, Wfinh, bfin, out);
}

// Round 6
// 161.210 us; speedup vs baseline: 5.5639x; 1.0456x over previous
//
#include <hip/hip_runtime.h>
#include <math.h>

#define N_   4
#define LQ_  5440
#define MQ_  (N_*LQ_)   // 21760 rows; /8 = 2720 blocks; /128 = 170 tiles

typedef _Float16 f16;
typedef __attribute__((ext_vector_type(2))) _Float16 f16x2;
typedef __attribute__((ext_vector_type(8))) _Float16 f16x8;
typedef __attribute__((ext_vector_type(4))) float     f32x4;

__device__ __forceinline__ unsigned short f2h(float f) {
  union { f16 h; unsigned short u; } v; v.h = (f16)f; return v.u;
}
__device__ __forceinline__ float h2f(unsigned u) {   // low 16 bits
  union { unsigned short u; f16 h; } v; v.u = (unsigned short)u; return (float)v.h;
}
__device__ __forceinline__ f16x2 u2h2(unsigned u) {
  union { unsigned u; f16x2 h; } v; v.u = u; return v.h;
}

#define GLD16(gp, lp) __builtin_amdgcn_global_load_lds( \
    (const __attribute__((address_space(1))) void*)(gp), \
    (__attribute__((address_space(3))) void*)(lp), 16, 0, 0)

// -------- all weight prep in ONE dispatch (grid = 675 blocks x 256) ------------
__global__ __launch_bounds__(256)
void prep(const float* __restrict__ W_val, const float* __restrict__ W_off,
          const float* __restrict__ W_attn, const float* __restrict__ W_agg,
          const float* __restrict__ W_out, const float* __restrict__ b_off,
          const float* __restrict__ b_attn, const float* __restrict__ b_agg,
          const float* __restrict__ b_out,
          unsigned short* __restrict__ Wvalh, unsigned short* __restrict__ Wcath,
          unsigned short* __restrict__ Wfinh, float* __restrict__ bcat,
          float* __restrict__ bfin) {
  __shared__ float wrow[256];
  const int b = blockIdx.x, t = threadIdx.x;
  if (b < 160) {
    const float* src; unsigned short* dst; int i;
    if (b < 64)       { src = W_val;  dst = Wvalh;          i = b * 256 + t; }
    else if (b < 128) { src = W_off;  dst = Wcath;          i = (b - 64) * 256 + t; }
    else              { src = W_attn; dst = Wcath + 65536;  i = (b - 128) * 256 + t; }
    float4 v = reinterpret_cast<const float4*>(src)[i];
    ushort4 r;
    r.x = f2h(v.x); r.y = f2h(v.y); r.z = f2h(v.z); r.w = f2h(v.w);
    reinterpret_cast<ushort4*>(dst)[i] = r;
  } else if (b < 672) {
    const int idx = b - 160, j = idx & 255, s = idx >> 8;
    wrow[t] = W_agg[(size_t)j * 512 + s * 256 + t];
    __syncthreads();
    float a = 0.f;
    for (int i = 0; i < 256; ++i) a = fmaf(wrow[i], W_out[(size_t)i * 256 + t], a);
    Wfinh[(size_t)j * 512 + s * 256 + t] = f2h(a);
  } else if (b == 672) {
    float s = b_agg[t];
    for (int i = 0; i < 256; ++i)
      s = fmaf(W_agg[(size_t)t * 512 + i] + W_agg[(size_t)t * 512 + 256 + i], b_out[i], s);
    bfin[t] = s;
  } else if (b == 673) {
    bcat[t] = b_off[t];
  } else {
    if (t < 128) bcat[256 + t] = b_attn[t];
  }
}

// -------- stage-1 GEMM with fused fp32->f16 A-staging --------------------------
__global__ __launch_bounds__(256)
void gemm_stage1(const float* __restrict__ q0, const float* __restrict__ q1,
                 const float* __restrict__ f0, const float* __restrict__ f1,
                 const unsigned short* __restrict__ Wvalh,
                 const unsigned short* __restrict__ Wcath,
                 const float* __restrict__ b_val, const float* __restrict__ bcat,
                 unsigned short* __restrict__ valb, unsigned short* __restrict__ oab) {
  __shared__ __align__(16) unsigned short As[128 * 64];
  __shared__ __align__(16) unsigned short Ws[128 * 64];
  const int y = blockIdx.y, z = blockIdx.z;
  const size_t SZ = (size_t)MQ_ * 256;
  const float* A; const unsigned short* W; const float* bias;
  unsigned short* C; int NC, col0;
  if (y < 2) { A = z ? f1 : f0; W = Wvalh; bias = b_val; C = valb + z * SZ;              NC = 256; col0 = y * 128; }
  else       { A = z ? q1 : q0; W = Wcath; bias = bcat;  C = oab + (size_t)z * MQ_ * 384; NC = 384; col0 = (y - 2) * 128; }

  const int t    = threadIdx.x;
  const int lane = t & 63;
  const int wv   = t >> 6;
  const int wr   = wv >> 1, wc = wv & 1;
  const int row0 = blockIdx.x * 128;
  const int srow = t >> 3, schunk = t & 7;
  const int wbase = wv * 512;

  f32x4 acc[4][4] = {};

  for (int k0 = 0; k0 < 256; k0 += 64) {
    __syncthreads();
    #pragma unroll
    for (int i = 0; i < 4; ++i) {                  // W: direct-to-LDS, pre-swizzled src
      const int row = i * 32 + srow;
      const int ch  = schunk ^ (row & 7);
      GLD16(W + (size_t)(col0 + row) * 256 + k0 + ch * 8, &Ws[i * 2048 + wbase]);
    }
    #pragma unroll
    for (int i = 0; i < 4; ++i) {                  // A: fp32 reg-stage + cvt
      const int row = i * 32 + srow;
      const float* src = A + (size_t)(row0 + row) * 256 + k0 + schunk * 8;
      const float4 a0 = *reinterpret_cast<const float4*>(src);
      const float4 a1 = *reinterpret_cast<const float4*>(src + 4);
      f16x8 hv;
      hv[0] = (f16)a0.x; hv[1] = (f16)a0.y; hv[2] = (f16)a0.z; hv[3] = (f16)a0.w;
      hv[4] = (f16)a1.x; hv[5] = (f16)a1.y; hv[6] = (f16)a1.z; hv[7] = (f16)a1.w;
      const int ch = schunk ^ (row & 7);
      *reinterpret_cast<f16x8*>(&As[row * 64 + ch * 8]) = hv;
    }
    __syncthreads();

    f16x8 af[4][2], bfr[4][2];
    #pragma unroll
    for (int f = 0; f < 4; ++f)
      #pragma unroll
      for (int kk = 0; kk < 2; ++kk) {
        const int ra = wr * 64 + f * 16 + (lane & 15);
        const int ca = (kk * 4 + (lane >> 4)) ^ (ra & 7);
        af[f][kk] = *(const f16x8*)&As[ra * 64 + ca * 8];
        const int rb = wc * 64 + f * 16 + (lane & 15);
        const int cb = (kk * 4 + (lane >> 4)) ^ (rb & 7);
        bfr[f][kk] = *(const f16x8*)&Ws[rb * 64 + cb * 8];
      }
    #pragma unroll
    for (int kk = 0; kk < 2; ++kk)
      #pragma unroll
      for (int fm = 0; fm < 4; ++fm)
        #pragma unroll
        for (int fn = 0; fn < 4; ++fn)
          acc[fm][fn] = __builtin_amdgcn_mfma_f32_16x16x32_f16(
              af[fm][kk], bfr[fn][kk], acc[fm][fn], 0, 0, 0);
  }

  #pragma unroll
  for (int fm = 0; fm < 4; ++fm) {
    const int m = row0 + wr * 64 + fm * 16 + (lane >> 4) * 4;
    #pragma unroll
    for (int fn = 0; fn < 4; ++fn) {
      const int c = col0 + wc * 64 + fn * 16 + (lane & 15);
      const float bv = bias[c];
      #pragma unroll
      for (int r = 0; r < 4; ++r)
        C[(size_t)(m + r) * NC + c] = f2h(acc[fm][fn][r] + bv);
    }
  }
}

// -------- final GEMM: out = acc(MQ,512 f16) @ Wfin^T + bfin, fp32 out ----------
__global__ __launch_bounds__(256)
void gemm_final(const unsigned short* __restrict__ A,
                const unsigned short* __restrict__ W,
                const float* __restrict__ bias, float* __restrict__ out) {
  __shared__ __align__(16) unsigned short As[128 * 64];
  __shared__ __align__(16) unsigned short Ws[128 * 64];
  const int t    = threadIdx.x;
  const int lane = t & 63;
  const int wv   = t >> 6;
  const int wr   = wv >> 1, wc = wv & 1;
  const int row0 = blockIdx.x * 128, col0 = blockIdx.y * 128;
  const int srow = t >> 3, schunk = t & 7;
  const int wbase = wv * 512;

  f32x4 acc[4][4] = {};

  for (int k0 = 0; k0 < 512; k0 += 64) {
    __syncthreads();
    #pragma unroll
    for (int i = 0; i < 4; ++i) {
      const int row = i * 32 + srow;
      const int ch  = schunk ^ (row & 7);
      GLD16(A + (size_t)(row0 + row) * 512 + k0 + ch * 8, &As[i * 2048 + wbase]);
      GLD16(W + (size_t)(col0 + row) * 512 + k0 + ch * 8, &Ws[i * 2048 + wbase]);
    }
    __syncthreads();

    f16x8 af[4][2], bfr[4][2];
    #pragma unroll
    for (int f = 0; f < 4; ++f)
      #pragma unroll
      for (int kk = 0; kk < 2; ++kk) {
        const int ra = wr * 64 + f * 16 + (lane & 15);
        const int ca = (kk * 4 + (lane >> 4)) ^ (ra & 7);
        af[f][kk] = *(const f16x8*)&As[ra * 64 + ca * 8];
        const int rb = wc * 64 + f * 16 + (lane & 15);
        const int cb = (kk * 4 + (lane >> 4)) ^ (rb & 7);
        bfr[f][kk] = *(const f16x8*)&Ws[rb * 64 + cb * 8];
      }
    #pragma unroll
    for (int kk = 0; kk < 2; ++kk)
      #pragma unroll
      for (int fm = 0; fm < 4; ++fm)
        #pragma unroll
        for (int fn = 0; fn < 4; ++fn)
          acc[fm][fn] = __builtin_amdgcn_mfma_f32_16x16x32_f16(
              af[fm][kk], bfr[fn][kk], acc[fm][fn], 0, 0, 0);
  }

  #pragma unroll
  for (int fm = 0; fm < 4; ++fm) {
    const int m = row0 + wr * 64 + fm * 16 + (lane >> 4) * 4;
    #pragma unroll
    for (int fn = 0; fn < 4; ++fn) {
      const int c = col0 + wc * 64 + fn * 16 + (lane & 15);
      const float bv = bias[c];
      #pragma unroll
      for (int r = 0; r < 4; ++r)
        out[(size_t)(m + r) * 256 + c] = acc[fm][fn][r] + bv;
    }
  }
}

// ------------------------- deformable sampling (both streams) ------------------
// grid (MQ/8, 2); block 256 = 8 queries x 32 threads. __launch_bounds__(256,4).
// Phase 1: thread tq owns head h=tq>>2, level l=tq&3, points p=0..3: softmax via
//   2 shfl_xor; store PRE-SCALED byte offsets (idx*512, uint4) in lds_i and
//   packed f16 weights (uint2) in lds_w, both at [q][j][h^(j&7)].
// Phase 2: thread=(q, h=tq>>2, dg=tq&3): per level-group buffer ALL 16 f16x8
//   gathers in regs (16-deep MLP) before consuming with v_pk_fma_f16.
__global__ __launch_bounds__(256, 4)
void deform_sample5(const unsigned short* __restrict__ vals,  // (2,N,LQ,256) f16
                    const unsigned short* __restrict__ oa,    // (2,MQ,384) f16
                    const float* __restrict__ refp,           // (N,LQ,4,2) f32
                    unsigned short* __restrict__ acc_out) {   // (MQ,512) f16
  const int s  = blockIdx.y;
  const int t  = threadIdx.x;
  const int q  = t >> 5, tq = t & 31;
  const int row = blockIdx.x * 8 + q;
  const int n  = row / LQ_;       // block-uniform: LQ_ % 8 == 0
  const int h  = tq >> 2;
  __shared__ uint4 lds_i[8][16][8];   // 16 KB: byte offsets (idx*512) x4 corners
  __shared__ uint2 lds_w[8][16][8];   //  8 KB: packed f16 weights x4 corners

  const unsigned short* oar = oa + ((size_t)s * MQ_ + row) * 384;
  {
    const int   l  = tq & 3;
    const int   Wn = 64 >> l;
    const float Wf = (float)Wn;
    const int   lb = (int)(((0xAD200u >> (5 * l)) & 31u) << 8);  // {0,4096,5120,5376}
    const uint4 ov = *reinterpret_cast<const uint4*>(oar + (size_t)tq * 8);
    const uint2 lv = *reinterpret_cast<const uint2*>(oar + 256 + (size_t)tq * 4);
    const float2 rxy = *reinterpret_cast<const float2*>(refp + (size_t)row * 8 + l * 2);
    float lg[4] = { h2f(lv.x), h2f(lv.x >> 16), h2f(lv.y), h2f(lv.y >> 16) };
    float mx = fmaxf(fmaxf(lg[0], lg[1]), fmaxf(lg[2], lg[3]));
    mx = fmaxf(mx, __shfl_xor(mx, 1));
    mx = fmaxf(mx, __shfl_xor(mx, 2));
    float e[4], se;
    #pragma unroll
    for (int k = 0; k < 4; ++k) e[k] = __expf(lg[k] - mx);
    se = (e[0] + e[1]) + (e[2] + e[3]);
    se += __shfl_xor(se, 1);
    se += __shfl_xor(se, 2);
    const float inv = 1.f / se;
    const unsigned od[4] = { ov.x, ov.y, ov.z, ov.w };
    #pragma unroll
    for (int k = 0; k < 4; ++k) {
      const float ox = h2f(od[k]), oy = h2f(od[k] >> 16);
      const float x = fmaf(rxy.x, Wf, ox) - 0.5f;
      const float y = fmaf(rxy.y, Wf, oy) - 0.5f;
      const float x0f = floorf(x), y0f = floorf(y);
      const int   x0 = (int)x0f,   y0 = (int)y0f;
      const float lx = x - x0f,    ly = y - y0f;
      const float aw = e[k] * inv;
      const int   xs[2] = {x0, x0 + 1}, ys[2] = {y0, y0 + 1};
      const float wx[2] = {1.f - lx, lx}, wy[2] = {1.f - ly, ly};
      unsigned ia[4]; unsigned short wa[4];
      #pragma unroll
      for (int cy = 0; cy < 2; ++cy)
        #pragma unroll
        for (int cx = 0; cx < 2; ++cx) {
          const int xi = xs[cx], yi = ys[cy];
          const bool v = (xi >= 0) && (xi < Wn) && (yi >= 0) && (yi < Wn);
          const int xc = min(max(xi, 0), Wn - 1), yc = min(max(yi, 0), Wn - 1);
          ia[cy * 2 + cx] = (unsigned)(lb + yc * Wn + xc) << 9;   // byte offset
          wa[cy * 2 + cx] = f2h(v ? wx[cx] * wy[cy] * aw : 0.f);
        }
      const int jj = l * 4 + k;
      const int hx = h ^ (jj & 7);
      lds_i[q][jj][hx] = make_uint4(ia[0], ia[1], ia[2], ia[3]);
      lds_w[q][jj][hx] = make_uint2((unsigned)wa[0] | ((unsigned)wa[1] << 16),
                                    (unsigned)wa[2] | ((unsigned)wa[3] << 16));
    }
  }
  __syncthreads();

  const int dg = tq & 3;
  const char* vb = (const char*)(vals + ((size_t)s * N_ + n) * LQ_ * 256);
  const unsigned hd = (unsigned)((h * 32 + dg * 8) * 2);   // byte offset in row
  float facc[8] = {};
  #pragma unroll 1
  for (int l4 = 0; l4 < 4; ++l4) {
    // gather ALL 16 values of this level group first (16-deep MLP)
    uint4 mi[4]; uint2 mw[4];
    #pragma unroll
    for (int p = 0; p < 4; ++p) {
      const int j = l4 * 4 + p;
      const int hx = h ^ (j & 7);
      mi[p] = lds_i[q][j][hx];
      mw[p] = lds_w[q][j][hx];
    }
    f16x8 v[16];
    #pragma unroll
    for (int p = 0; p < 4; ++p) {
      v[p * 4 + 0] = *reinterpret_cast<const f16x8*>(vb + (mi[p].x + hd));
      v[p * 4 + 1] = *reinterpret_cast<const f16x8*>(vb + (mi[p].y + hd));
      v[p * 4 + 2] = *reinterpret_cast<const f16x8*>(vb + (mi[p].z + hd));
      v[p * 4 + 3] = *reinterpret_cast<const f16x8*>(vb + (mi[p].w + hd));
    }
    f16x2 a0 = {0, 0}, a1 = {0, 0}, a2 = {0, 0}, a3 = {0, 0};
    #pragma unroll
    for (int p = 0; p < 4; ++p) {
      const f16x2 w0 = u2h2(__builtin_amdgcn_perm(mw[p].x, mw[p].x, 0x01000100u));
      const f16x2 w1 = u2h2(__builtin_amdgcn_perm(mw[p].x, mw[p].x, 0x03020302u));
      const f16x2 w2 = u2h2(__builtin_amdgcn_perm(mw[p].y, mw[p].y, 0x01000100u));
      const f16x2 w3 = u2h2(__builtin_amdgcn_perm(mw[p].y, mw[p].y, 0x03020302u));
      const f16x2* p0 = (const f16x2*)&v[p * 4 + 0];
      const f16x2* p1 = (const f16x2*)&v[p * 4 + 1];
      const f16x2* p2 = (const f16x2*)&v[p * 4 + 2];
      const f16x2* p3 = (const f16x2*)&v[p * 4 + 3];
      a0 = __builtin_elementwise_fma(p0[0], w0, a0);
      a1 = __builtin_elementwise_fma(p0[1], w0, a1);
      a2 = __builtin_elementwise_fma(p0[2], w0, a2);
      a3 = __builtin_elementwise_fma(p0[3], w0, a3);
      a0 = __builtin_elementwise_fma(p1[0], w1, a0);
      a1 = __builtin_elementwise_fma(p1[1], w1, a1);
      a2 = __builtin_elementwise_fma(p1[2], w1, a2);
      a3 = __builtin_elementwise_fma(p1[3], w1, a3);
      a0 = __builtin_elementwise_fma(p2[0], w2, a0);
      a1 = __builtin_elementwise_fma(p2[1], w2, a1);
      a2 = __builtin_elementwise_fma(p2[2], w2, a2);
      a3 = __builtin_elementwise_fma(p2[3], w2, a3);
      a0 = __builtin_elementwise_fma(p3[0], w3, a0);
      a1 = __builtin_elementwise_fma(p3[1], w3, a1);
      a2 = __builtin_elementwise_fma(p3[2], w3, a2);
      a3 = __builtin_elementwise_fma(p3[3], w3, a3);
    }
    facc[0] += (float)a0[0]; facc[1] += (float)a0[1];
    facc[2] += (float)a1[0]; facc[3] += (float)a1[1];
    facc[4] += (float)a2[0]; facc[5] += (float)a2[1];
    facc[6] += (float)a3[0]; facc[7] += (float)a3[1];
  }
  f16x8 r;
  #pragma unroll
  for (int e2 = 0; e2 < 8; ++e2) r[e2] = (f16)facc[e2];
  *reinterpret_cast<f16x8*>(acc_out + (size_t)row * 512 + s * 256 + h * 32 + dg * 8) = r;
}

// -------------------------------- launcher -------------------------------------
extern "C" void kernel_launch(void* const* d_in, const int* in_sizes, int n_in,
                              void* d_out, int out_size, void* d_ws, size_t ws_size,
                              hipStream_t stream) {
  const float* query0 = (const float*)d_in[0];
  const float* query1 = (const float*)d_in[1];
  const float* feat0  = (const float*)d_in[2];
  const float* feat1  = (const float*)d_in[3];
  const float* refp   = (const float*)d_in[4];
  const float* W_off  = (const float*)d_in[5];
  const float* b_off  = (const float*)d_in[6];
  const float* W_attn = (const float*)d_in[7];
  const float* b_attn = (const float*)d_in[8];
  const float* W_val  = (const float*)d_in[9];
  const float* b_val  = (const float*)d_in[10];
  const float* W_out  = (const float*)d_in[11];
  const float* b_out  = (const float*)d_in[12];
  const float* W_agg  = (const float*)d_in[13];
  const float* b_agg  = (const float*)d_in[14];
  float* out = (float*)d_out;

  char* p = (char*)d_ws;
  const size_t SZ = (size_t)MQ_ * 256;                 // elems per (MQ,256)
  unsigned short* valb  = (unsigned short*)p; p += 2 * SZ * 2;
  unsigned short* oab   = (unsigned short*)p; p += (size_t)2 * MQ_ * 384 * 2;
  unsigned short* accb  = (unsigned short*)p; p += (size_t)MQ_ * 512 * 2;
  unsigned short* Wvalh = (unsigned short*)p; p += 256 * 256 * 2;
  unsigned short* Wcath = (unsigned short*)p; p += 384 * 256 * 2;
  unsigned short* Wfinh = (unsigned short*)p; p += 256 * 512 * 2;
  float* bcat = (float*)p; p += 384 * 4;
  float* bfin = (float*)p; p += 256 * 4;

  prep<<<675, 256, 0, stream>>>(W_val, W_off, W_attn, W_agg, W_out, b_off, b_attn,
                                b_agg, b_out, Wvalh, Wcath, Wfinh, bcat, bfin);
  // val (y<2) + off/attn (y>=2) projections, both streams, fused fp32 cvt
  gemm_stage1<<<dim3(170, 5, 2), 256, 0, stream>>>(query0, query1, feat0, feat1,
                                                   Wvalh, Wcath, b_val, bcat,
                                                   valb, oab);
  // sampling, both streams, acc interleaved (MQ,512)
  deform_sample5<<<dim3(MQ_ / 8, 2), 256, 0, stream>>>(valb, oab, refp, accb);
  // final fused out+agg projection: K=512
  gemm_final<<<dim3(170, 2), 256, 0, stream>>>(accb, Wfinh, bfin, out);
}

// Round 7
// 158.625 us; speedup vs baseline: 5.6546x; 1.0163x over previous
//
#include <hip/hip_runtime.h>
#include <math.h>

#define N_   4
#define LQ_  5440
#define MQ_  (N_*LQ_)   // 21760 rows; /8 = 2720 blocks; /128 = 170 tiles

typedef _Float16 f16;
typedef __attribute__((ext_vector_type(2))) _Float16 f16x2;
typedef __attribute__((ext_vector_type(8))) _Float16 f16x8;
typedef __attribute__((ext_vector_type(4))) float     f32x4;

__device__ __forceinline__ unsigned short f2h(float f) {
  union { f16 h; unsigned short u; } v; v.h = (f16)f; return v.u;
}
__device__ __forceinline__ float h2f(unsigned u) {   // low 16 bits
  union { unsigned short u; f16 h; } v; v.u = (unsigned short)u; return (float)v.h;
}
__device__ __forceinline__ f16x2 u2h2(unsigned u) {
  union { unsigned u; f16x2 h; } v; v.u = u; return v.h;
}

#define GLD16(gp, lp) __builtin_amdgcn_global_load_lds( \
    (const __attribute__((address_space(1))) void*)(gp), \
    (__attribute__((address_space(3))) void*)(lp), 16, 0, 0)

// -------- all weight prep in ONE dispatch (grid = 675 blocks x 256) ------------
__global__ __launch_bounds__(256)
void prep(const float* __restrict__ W_val, const float* __restrict__ W_off,
          const float* __restrict__ W_attn, const float* __restrict__ W_agg,
          const float* __restrict__ W_out, const float* __restrict__ b_off,
          const float* __restrict__ b_attn, const float* __restrict__ b_agg,
          const float* __restrict__ b_out,
          unsigned short* __restrict__ Wvalh, unsigned short* __restrict__ Wcath,
          unsigned short* __restrict__ Wfinh, float* __restrict__ bcat,
          float* __restrict__ bfin) {
  __shared__ float wrow[256];
  const int b = blockIdx.x, t = threadIdx.x;
  if (b < 160) {
    const float* src; unsigned short* dst; int i;
    if (b < 64)       { src = W_val;  dst = Wvalh;          i = b * 256 + t; }
    else if (b < 128) { src = W_off;  dst = Wcath;          i = (b - 64) * 256 + t; }
    else              { src = W_attn; dst = Wcath + 65536;  i = (b - 128) * 256 + t; }
    float4 v = reinterpret_cast<const float4*>(src)[i];
    ushort4 r;
    r.x = f2h(v.x); r.y = f2h(v.y); r.z = f2h(v.z); r.w = f2h(v.w);
    reinterpret_cast<ushort4*>(dst)[i] = r;
  } else if (b < 672) {
    const int idx = b - 160, j = idx & 255, s = idx >> 8;
    wrow[t] = W_agg[(size_t)j * 512 + s * 256 + t];
    __syncthreads();
    float a = 0.f;
    for (int i = 0; i < 256; ++i) a = fmaf(wrow[i], W_out[(size_t)i * 256 + t], a);
    Wfinh[(size_t)j * 512 + s * 256 + t] = f2h(a);
  } else if (b == 672) {
    float s = b_agg[t];
    for (int i = 0; i < 256; ++i)
      s = fmaf(W_agg[(size_t)t * 512 + i] + W_agg[(size_t)t * 512 + 256 + i], b_out[i], s);
    bfin[t] = s;
  } else if (b == 673) {
    bcat[t] = b_off[t];
  } else {
    if (t < 128) bcat[256 + t] = b_attn[t];
  }
}

// -------- stage-1 GEMM, col-tile loop INSIDE the block --------------------------
// grid (170, src, stream): src 0 = feat->val (NC=256, 2 tiles), 1 = query->oa
// (NC=384, 3 tiles). Each block reads its fp32 A panel once cold; col-tile
// re-reads hit the same XCD's L2. A: reg-stage fp32->f16->LDS; W: global_load_lds.
__global__ __launch_bounds__(256)
void gemm_stage1(const float* __restrict__ q0, const float* __restrict__ q1,
                 const float* __restrict__ f0, const float* __restrict__ f1,
                 const unsigned short* __restrict__ Wvalh,
                 const unsigned short* __restrict__ Wcath,
                 const float* __restrict__ b_val, const float* __restrict__ bcat,
                 unsigned short* __restrict__ valb, unsigned short* __restrict__ oab) {
  __shared__ __align__(16) unsigned short As[128 * 64];
  __shared__ __align__(16) unsigned short Ws[128 * 64];
  const int src = blockIdx.y, z = blockIdx.z;
  const size_t SZ = (size_t)MQ_ * 256;
  const float* A; const unsigned short* W; const float* bias;
  unsigned short* C; int NC, NT;
  if (src == 0) { A = z ? f1 : f0; W = Wvalh; bias = b_val; C = valb + z * SZ;               NC = 256; NT = 2; }
  else          { A = z ? q1 : q0; W = Wcath; bias = bcat;  C = oab + (size_t)z * MQ_ * 384; NC = 384; NT = 3; }

  const int t    = threadIdx.x;
  const int lane = t & 63;
  const int wv   = t >> 6;
  const int wr   = wv >> 1, wc = wv & 1;
  const int row0 = blockIdx.x * 128;
  const int srow = t >> 3, schunk = t & 7;
  const int wbase = wv * 512;

  for (int ct = 0; ct < NT; ++ct) {
    const int col0 = ct * 128;
    f32x4 acc[4][4] = {};

    for (int k0 = 0; k0 < 256; k0 += 64) {
      __syncthreads();
      #pragma unroll
      for (int i = 0; i < 4; ++i) {                // W: direct-to-LDS, pre-swizzled src
        const int row = i * 32 + srow;
        const int ch  = schunk ^ (row & 7);
        GLD16(W + (size_t)(col0 + row) * 256 + k0 + ch * 8, &Ws[i * 2048 + wbase]);
      }
      #pragma unroll
      for (int i = 0; i < 4; ++i) {                // A: fp32 reg-stage + cvt (L2-hot on ct>0)
        const int row = i * 32 + srow;
        const float* srcp = A + (size_t)(row0 + row) * 256 + k0 + schunk * 8;
        const float4 a0 = *reinterpret_cast<const float4*>(srcp);
        const float4 a1 = *reinterpret_cast<const float4*>(srcp + 4);
        f16x8 hv;
        hv[0] = (f16)a0.x; hv[1] = (f16)a0.y; hv[2] = (f16)a0.z; hv[3] = (f16)a0.w;
        hv[4] = (f16)a1.x; hv[5] = (f16)a1.y; hv[6] = (f16)a1.z; hv[7] = (f16)a1.w;
        const int ch = schunk ^ (row & 7);
        *reinterpret_cast<f16x8*>(&As[row * 64 + ch * 8]) = hv;
      }
      __syncthreads();

      f16x8 af[4][2], bfr[4][2];
      #pragma unroll
      for (int f = 0; f < 4; ++f)
        #pragma unroll
        for (int kk = 0; kk < 2; ++kk) {
          const int ra = wr * 64 + f * 16 + (lane & 15);
          const int ca = (kk * 4 + (lane >> 4)) ^ (ra & 7);
          af[f][kk] = *(const f16x8*)&As[ra * 64 + ca * 8];
          const int rb = wc * 64 + f * 16 + (lane & 15);
          const int cb = (kk * 4 + (lane >> 4)) ^ (rb & 7);
          bfr[f][kk] = *(const f16x8*)&Ws[rb * 64 + cb * 8];
        }
      #pragma unroll
      for (int kk = 0; kk < 2; ++kk)
        #pragma unroll
        for (int fm = 0; fm < 4; ++fm)
          #pragma unroll
          for (int fn = 0; fn < 4; ++fn)
            acc[fm][fn] = __builtin_amdgcn_mfma_f32_16x16x32_f16(
                af[fm][kk], bfr[fn][kk], acc[fm][fn], 0, 0, 0);
    }

    #pragma unroll
    for (int fm = 0; fm < 4; ++fm) {
      const int m = row0 + wr * 64 + fm * 16 + (lane >> 4) * 4;
      #pragma unroll
      for (int fn = 0; fn < 4; ++fn) {
        const int c = col0 + wc * 64 + fn * 16 + (lane & 15);
        const float bv = bias[c];
        #pragma unroll
        for (int r = 0; r < 4; ++r)
          C[(size_t)(m + r) * NC + c] = f2h(acc[fm][fn][r] + bv);
      }
    }
  }
}

// -------- final GEMM: out = acc(MQ,512 f16) @ Wfin^T + bfin, fp32 out ----------
__global__ __launch_bounds__(256)
void gemm_final(const unsigned short* __restrict__ A,
                const unsigned short* __restrict__ W,
                const float* __restrict__ bias, float* __restrict__ out) {
  __shared__ __align__(16) unsigned short As[128 * 64];
  __shared__ __align__(16) unsigned short Ws[128 * 64];
  const int t    = threadIdx.x;
  const int lane = t & 63;
  const int wv   = t >> 6;
  const int wr   = wv >> 1, wc = wv & 1;
  const int row0 = blockIdx.x * 128, col0 = blockIdx.y * 128;
  const int srow = t >> 3, schunk = t & 7;
  const int wbase = wv * 512;

  f32x4 acc[4][4] = {};

  for (int k0 = 0; k0 < 512; k0 += 64) {
    __syncthreads();
    #pragma unroll
    for (int i = 0; i < 4; ++i) {
      const int row = i * 32 + srow;
      const int ch  = schunk ^ (row & 7);
      GLD16(A + (size_t)(row0 + row) * 512 + k0 + ch * 8, &As[i * 2048 + wbase]);
      GLD16(W + (size_t)(col0 + row) * 512 + k0 + ch * 8, &Ws[i * 2048 + wbase]);
    }
    __syncthreads();

    f16x8 af[4][2], bfr[4][2];
    #pragma unroll
    for (int f = 0; f < 4; ++f)
      #pragma unroll
      for (int kk = 0; kk < 2; ++kk) {
        const int ra = wr * 64 + f * 16 + (lane & 15);
        const int ca = (kk * 4 + (lane >> 4)) ^ (ra & 7);
        af[f][kk] = *(const f16x8*)&As[ra * 64 + ca * 8];
        const int rb = wc * 64 + f * 16 + (lane & 15);
        const int cb = (kk * 4 + (lane >> 4)) ^ (rb & 7);
        bfr[f][kk] = *(const f16x8*)&Ws[rb * 64 + cb * 8];
      }
    #pragma unroll
    for (int kk = 0; kk < 2; ++kk)
      #pragma unroll
      for (int fm = 0; fm < 4; ++fm)
        #pragma unroll
        for (int fn = 0; fn < 4; ++fn)
          acc[fm][fn] = __builtin_amdgcn_mfma_f32_16x16x32_f16(
              af[fm][kk], bfr[fn][kk], acc[fm][fn], 0, 0, 0);
  }

  #pragma unroll
  for (int fm = 0; fm < 4; ++fm) {
    const int m = row0 + wr * 64 + fm * 16 + (lane >> 4) * 4;
    #pragma unroll
    for (int fn = 0; fn < 4; ++fn) {
      const int c = col0 + wc * 64 + fn * 16 + (lane & 15);
      const float bv = bias[c];
      #pragma unroll
      for (int r = 0; r < 4; ++r)
        out[(size_t)(m + r) * 256 + c] = acc[fm][fn][r] + bv;
    }
  }
}

// ------------------------- deformable sampling (both streams) ------------------
// grid (MQ/8, 2); block 256 = 8 queries x 32 threads.
// Phase 1: thread tq owns head h=tq>>2, level l=tq&3, points p=0..3: softmax via
//   2 shfl_xor; pack per point ONE uint4 {idx01, idx23, w01, w23} with 16-BIT
//   element-row indices at lds[q][j][h^(j&7)] -> 16 KB total (occupancy).
// Phase 2: thread=(q, h=tq>>2, dg=tq&3): per level-group buffer ALL 16 f16x8
//   gathers (addr = idx<<9 + hd via lshl_add) before consuming with v_pk_fma_f16.
__global__ __launch_bounds__(256, 4)
void deform_sample6(const unsigned short* __restrict__ vals,  // (2,N,LQ,256) f16
                    const unsigned short* __restrict__ oa,    // (2,MQ,384) f16
                    const float* __restrict__ refp,           // (N,LQ,4,2) f32
                    unsigned short* __restrict__ acc_out) {   // (MQ,512) f16
  const int s  = blockIdx.y;
  const int t  = threadIdx.x;
  const int q  = t >> 5, tq = t & 31;
  const int row = blockIdx.x * 8 + q;
  const int n  = row / LQ_;       // block-uniform: LQ_ % 8 == 0
  const int h  = tq >> 2;
  __shared__ uint4 lds_rec[8][16][8];   // 16 KB: {idx01, idx23, w01, w23}

  const unsigned short* oar = oa + ((size_t)s * MQ_ + row) * 384;
  {
    const int   l  = tq & 3;
    const int   Wn = 64 >> l;
    const float Wf = (float)Wn;
    const int   lb = (int)(((0xAD200u >> (5 * l)) & 31u) << 8);  // {0,4096,5120,5376}
    const uint4 ov = *reinterpret_cast<const uint4*>(oar + (size_t)tq * 8);
    const uint2 lv = *reinterpret_cast<const uint2*>(oar + 256 + (size_t)tq * 4);
    const float2 rxy = *reinterpret_cast<const float2*>(refp + (size_t)row * 8 + l * 2);
    float lg[4] = { h2f(lv.x), h2f(lv.x >> 16), h2f(lv.y), h2f(lv.y >> 16) };
    float mx = fmaxf(fmaxf(lg[0], lg[1]), fmaxf(lg[2], lg[3]));
    mx = fmaxf(mx, __shfl_xor(mx, 1));
    mx = fmaxf(mx, __shfl_xor(mx, 2));
    float e[4], se;
    #pragma unroll
    for (int k = 0; k < 4; ++k) e[k] = __expf(lg[k] - mx);
    se = (e[0] + e[1]) + (e[2] + e[3]);
    se += __shfl_xor(se, 1);
    se += __shfl_xor(se, 2);
    const float inv = 1.f / se;
    const unsigned od[4] = { ov.x, ov.y, ov.z, ov.w };
    #pragma unroll
    for (int k = 0; k < 4; ++k) {
      const float ox = h2f(od[k]), oy = h2f(od[k] >> 16);
      const float x = fmaf(rxy.x, Wf, ox) - 0.5f;
      const float y = fmaf(rxy.y, Wf, oy) - 0.5f;
      const float x0f = floorf(x), y0f = floorf(y);
      const int   x0 = (int)x0f,   y0 = (int)y0f;
      const float lx = x - x0f,    ly = y - y0f;
      const float aw = e[k] * inv;
      const int   xs[2] = {x0, x0 + 1}, ys[2] = {y0, y0 + 1};
      const float wx[2] = {1.f - lx, lx}, wy[2] = {1.f - ly, ly};
      unsigned ia[4]; unsigned short wa[4];
      #pragma unroll
      for (int cy = 0; cy < 2; ++cy)
        #pragma unroll
        for (int cx = 0; cx < 2; ++cx) {
          const int xi = xs[cx], yi = ys[cy];
          const bool v = (xi >= 0) && (xi < Wn) && (yi >= 0) && (yi < Wn);
          const int xc = min(max(xi, 0), Wn - 1), yc = min(max(yi, 0), Wn - 1);
          ia[cy * 2 + cx] = (unsigned)(lb + yc * Wn + xc);       // 16-bit row idx
          wa[cy * 2 + cx] = f2h(v ? wx[cx] * wy[cy] * aw : 0.f);
        }
      const int jj = l * 4 + k;
      uint4 rec;
      rec.x = ia[0] | (ia[1] << 16);
      rec.y = ia[2] | (ia[3] << 16);
      rec.z = (unsigned)wa[0] | ((unsigned)wa[1] << 16);
      rec.w = (unsigned)wa[2] | ((unsigned)wa[3] << 16);
      lds_rec[q][jj][h ^ (jj & 7)] = rec;
    }
  }
  __syncthreads();

  const int dg = tq & 3;
  const char* vb = (const char*)(vals + ((size_t)s * N_ + n) * LQ_ * 256);
  const unsigned hd = (unsigned)((h * 32 + dg * 8) * 2);   // byte offset in row
  float facc[8] = {};
  #pragma unroll 1
  for (int l4 = 0; l4 < 4; ++l4) {
    uint4 m[4];
    #pragma unroll
    for (int p = 0; p < 4; ++p) {
      const int j = l4 * 4 + p;
      m[p] = lds_rec[q][j][h ^ (j & 7)];
    }
    f16x8 v[16];
    #pragma unroll
    for (int p = 0; p < 4; ++p) {
      v[p * 4 + 0] = *reinterpret_cast<const f16x8*>(vb + (((m[p].x & 0xffffu) << 9) + hd));
      v[p * 4 + 1] = *reinterpret_cast<const f16x8*>(vb + (((m[p].x >> 16) << 9) + hd));
      v[p * 4 + 2] = *reinterpret_cast<const f16x8*>(vb + (((m[p].y & 0xffffu) << 9) + hd));
      v[p * 4 + 3] = *reinterpret_cast<const f16x8*>(vb + (((m[p].y >> 16) << 9) + hd));
    }
    f16x2 a0 = {0, 0}, a1 = {0, 0}, a2 = {0, 0}, a3 = {0, 0};
    #pragma unroll
    for (int p = 0; p < 4; ++p) {
      const f16x2 w0 = u2h2(__builtin_amdgcn_perm(m[p].z, m[p].z, 0x01000100u));
      const f16x2 w1 = u2h2(__builtin_amdgcn_perm(m[p].z, m[p].z, 0x03020302u));
      const f16x2 w2 = u2h2(__builtin_amdgcn_perm(m[p].w, m[p].w, 0x01000100u));
      const f16x2 w3 = u2h2(__builtin_amdgcn_perm(m[p].w, m[p].w, 0x03020302u));
      const f16x2* p0 = (const f16x2*)&v[p * 4 + 0];
      const f16x2* p1 = (const f16x2*)&v[p * 4 + 1];
      const f16x2* p2 = (const f16x2*)&v[p * 4 + 2];
      const f16x2* p3 = (const f16x2*)&v[p * 4 + 3];
      a0 = __builtin_elementwise_fma(p0[0], w0, a0);
      a1 = __builtin_elementwise_fma(p0[1], w0, a1);
      a2 = __builtin_elementwise_fma(p0[2], w0, a2);
      a3 = __builtin_elementwise_fma(p0[3], w0, a3);
      a0 = __builtin_elementwise_fma(p1[0], w1, a0);
      a1 = __builtin_elementwise_fma(p1[1], w1, a1);
      a2 = __builtin_elementwise_fma(p1[2], w1, a2);
      a3 = __builtin_elementwise_fma(p1[3], w1, a3);
      a0 = __builtin_elementwise_fma(p2[0], w2, a0);
      a1 = __builtin_elementwise_fma(p2[1], w2, a1);
      a2 = __builtin_elementwise_fma(p2[2], w2, a2);
      a3 = __builtin_elementwise_fma(p2[3], w2, a3);
      a0 = __builtin_elementwise_fma(p3[0], w3, a0);
      a1 = __builtin_elementwise_fma(p3[1], w3, a1);
      a2 = __builtin_elementwise_fma(p3[2], w3, a2);
      a3 = __builtin_elementwise_fma(p3[3], w3, a3);
    }
    facc[0] += (float)a0[0]; facc[1] += (float)a0[1];
    facc[2] += (float)a1[0]; facc[3] += (float)a1[1];
    facc[4] += (float)a2[0]; facc[5] += (float)a2[1];
    facc[6] += (float)a3[0]; facc[7] += (float)a3[1];
  }
  f16x8 r;
  #pragma unroll
  for (int e2 = 0; e2 < 8; ++e2) r[e2] = (f16)facc[e2];
  *reinterpret_cast<f16x8*>(acc_out + (size_t)row * 512 + s * 256 + h * 32 + dg * 8) = r;
}

// -------------------------------- launcher -------------------------------------
extern "C" void kernel_launch(void* const* d_in, const int* in_sizes, int n_in,
                              void* d_out, int out_size, void* d_ws, size_t ws_size,
                              hipStream_t stream) {
  const float* query0 = (const float*)d_in[0];
  const float* query1 = (const float*)d_in[1];
  const float* feat0  = (const float*)d_in[2];
  const float* feat1  = (const float*)d_in[3];
  const float* refp   = (const float*)d_in[4];
  const float* W_off  = (const float*)d_in[5];
  const float* b_off  = (const float*)d_in[6];
  const float* W_attn = (const float*)d_in[7];
  const float* b_attn = (const float*)d_in[8];
  const float* W_val  = (const float*)d_in[9];
  const float* b_val  = (const float*)d_in[10];
  const float* W_out  = (const float*)d_in[11];
  const float* b_out  = (const float*)d_in[12];
  const float* W_agg  = (const float*)d_in[13];
  const float* b_agg  = (const float*)d_in[14];
  float* out = (float*)d_out;

  char* p = (char*)d_ws;
  const size_t SZ = (size_t)MQ_ * 256;                 // elems per (MQ,256)
  unsigned short* valb  = (unsigned short*)p; p += 2 * SZ * 2;
  unsigned short* oab   = (unsigned short*)p; p += (size_t)2 * MQ_ * 384 * 2;
  unsigned short* accb  = (unsigned short*)p; p += (size_t)MQ_ * 512 * 2;
  unsigned short* Wvalh = (unsigned short*)p; p += 256 * 256 * 2;
  unsigned short* Wcath = (unsigned short*)p; p += 384 * 256 * 2;
  unsigned short* Wfinh = (unsigned short*)p; p += 256 * 512 * 2;
  float* bcat = (float*)p; p += 384 * 4;
  float* bfin = (float*)p; p += 256 * 4;

  prep<<<675, 256, 0, stream>>>(W_val, W_off, W_attn, W_agg, W_out, b_off, b_attn,
                                b_agg, b_out, Wvalh, Wcath, Wfinh, bcat, bfin);
  // val (src=0) + off/attn (src=1) projections, both streams, col-tiles in-block
  gemm_stage1<<<dim3(170, 2, 2), 256, 0, stream>>>(query0, query1, feat0, feat1,
                                                   Wvalh, Wcath, b_val, bcat,
                                                   valb, oab);
  // sampling, both streams, acc interleaved (MQ,512)
  deform_sample6<<<dim3(MQ_ / 8, 2), 256, 0, stream>>>(valb, oab, refp, accb);
  // final fused out+agg projection: K=512
  gemm_final<<<dim3(170, 2), 256, 0, stream>>>(accb, Wfinh, bfin, out);
}

// Round 8
// 138.042 us; speedup vs baseline: 6.4977x; 1.1491x over previous
//
#include <hip/hip_runtime.h>
#include <math.h>

#define N_   4
#define LQ_  5440
#define MQ_  (N_*LQ_)   // 21760 rows; /8 = 2720 blocks; /128 = 170 tiles

typedef _Float16 f16;
typedef __attribute__((ext_vector_type(2))) _Float16 f16x2;
typedef __attribute__((ext_vector_type(8))) _Float16 f16x8;
typedef __attribute__((ext_vector_type(4))) float     f32x4;

__device__ __forceinline__ unsigned short f2h(float f) {
  union { f16 h; unsigned short u; } v; v.h = (f16)f; return v.u;
}
__device__ __forceinline__ float h2f(unsigned u) {   // low 16 bits
  union { unsigned short u; f16 h; } v; v.u = (unsigned short)u; return (float)v.h;
}
__device__ __forceinline__ f16x2 u2h2(unsigned u) {
  union { unsigned u; f16x2 h; } v; v.u = u; return v.h;
}

#define GLD16(gp, lp) __builtin_amdgcn_global_load_lds( \
    (const __attribute__((address_space(1))) void*)(gp), \
    (__attribute__((address_space(3))) void*)(lp), 16, 0, 0)

// -------- all weight prep in ONE dispatch (grid = 675 blocks x 256) ------------
__global__ __launch_bounds__(256)
void prep(const float* __restrict__ W_val, const float* __restrict__ W_off,
          const float* __restrict__ W_attn, const float* __restrict__ W_agg,
          const float* __restrict__ W_out, const float* __restrict__ b_off,
          const float* __restrict__ b_attn, const float* __restrict__ b_agg,
          const float* __restrict__ b_out,
          unsigned short* __restrict__ Wvalh, unsigned short* __restrict__ Wcath,
          unsigned short* __restrict__ Wfinh, float* __restrict__ bcat,
          float* __restrict__ bfin) {
  __shared__ float wrow[256];
  const int b = blockIdx.x, t = threadIdx.x;
  if (b < 160) {
    const float* src; unsigned short* dst; int i;
    if (b < 64)       { src = W_val;  dst = Wvalh;          i = b * 256 + t; }
    else if (b < 128) { src = W_off;  dst = Wcath;          i = (b - 64) * 256 + t; }
    else              { src = W_attn; dst = Wcath + 65536;  i = (b - 128) * 256 + t; }
    float4 v = reinterpret_cast<const float4*>(src)[i];
    ushort4 r;
    r.x = f2h(v.x); r.y = f2h(v.y); r.z = f2h(v.z); r.w = f2h(v.w);
    reinterpret_cast<ushort4*>(dst)[i] = r;
  } else if (b < 672) {
    const int idx = b - 160, j = idx & 255, s = idx >> 8;
    wrow[t] = W_agg[(size_t)j * 512 + s * 256 + t];
    __syncthreads();
    float a = 0.f;
    for (int i = 0; i < 256; ++i) a = fmaf(wrow[i], W_out[(size_t)i * 256 + t], a);
    Wfinh[(size_t)j * 512 + s * 256 + t] = f2h(a);
  } else if (b == 672) {
    float s = b_agg[t];
    for (int i = 0; i < 256; ++i)
      s = fmaf(W_agg[(size_t)t * 512 + i] + W_agg[(size_t)t * 512 + 256 + i], b_out[i], s);
    bfin[t] = s;
  } else if (b == 673) {
    bcat[t] = b_off[t];
  } else {
    if (t < 128) bcat[256 + t] = b_attn[t];
  }
}

// -------- stage-1 GEMM, col-tile loop INSIDE the block --------------------------
__global__ __launch_bounds__(256)
void gemm_stage1(const float* __restrict__ q0, const float* __restrict__ q1,
                 const float* __restrict__ f0, const float* __restrict__ f1,
                 const unsigned short* __restrict__ Wvalh,
                 const unsigned short* __restrict__ Wcath,
                 const float* __restrict__ b_val, const float* __restrict__ bcat,
                 unsigned short* __restrict__ valb, unsigned short* __restrict__ oab) {
  __shared__ __align__(16) unsigned short As[128 * 64];
  __shared__ __align__(16) unsigned short Ws[128 * 64];
  const int src = blockIdx.y, z = blockIdx.z;
  const size_t SZ = (size_t)MQ_ * 256;
  const float* A; const unsigned short* W; const float* bias;
  unsigned short* C; int NC, NT;
  if (src == 0) { A = z ? f1 : f0; W = Wvalh; bias = b_val; C = valb + z * SZ;               NC = 256; NT = 2; }
  else          { A = z ? q1 : q0; W = Wcath; bias = bcat;  C = oab + (size_t)z * MQ_ * 384; NC = 384; NT = 3; }

  const int t    = threadIdx.x;
  const int lane = t & 63;
  const int wv   = t >> 6;
  const int wr   = wv >> 1, wc = wv & 1;
  const int row0 = blockIdx.x * 128;
  const int srow = t >> 3, schunk = t & 7;
  const int wbase = wv * 512;

  for (int ct = 0; ct < NT; ++ct) {
    const int col0 = ct * 128;
    f32x4 acc[4][4] = {};

    for (int k0 = 0; k0 < 256; k0 += 64) {
      __syncthreads();
      #pragma unroll
      for (int i = 0; i < 4; ++i) {                // W: direct-to-LDS, pre-swizzled src
        const int row = i * 32 + srow;
        const int ch  = schunk ^ (row & 7);
        GLD16(W + (size_t)(col0 + row) * 256 + k0 + ch * 8, &Ws[i * 2048 + wbase]);
      }
      #pragma unroll
      for (int i = 0; i < 4; ++i) {                // A: fp32 reg-stage + cvt (L2-hot on ct>0)
        const int row = i * 32 + srow;
        const float* srcp = A + (size_t)(row0 + row) * 256 + k0 + schunk * 8;
        const float4 a0 = *reinterpret_cast<const float4*>(srcp);
        const float4 a1 = *reinterpret_cast<const float4*>(srcp + 4);
        f16x8 hv;
        hv[0] = (f16)a0.x; hv[1] = (f16)a0.y; hv[2] = (f16)a0.z; hv[3] = (f16)a0.w;
        hv[4] = (f16)a1.x; hv[5] = (f16)a1.y; hv[6] = (f16)a1.z; hv[7] = (f16)a1.w;
        const int ch = schunk ^ (row & 7);
        *reinterpret_cast<f16x8*>(&As[row * 64 + ch * 8]) = hv;
      }
      __syncthreads();

      f16x8 af[4][2], bfr[4][2];
      #pragma unroll
      for (int f = 0; f < 4; ++f)
        #pragma unroll
        for (int kk = 0; kk < 2; ++kk) {
          const int ra = wr * 64 + f * 16 + (lane & 15);
          const int ca = (kk * 4 + (lane >> 4)) ^ (ra & 7);
          af[f][kk] = *(const f16x8*)&As[ra * 64 + ca * 8];
          const int rb = wc * 64 + f * 16 + (lane & 15);
          const int cb = (kk * 4 + (lane >> 4)) ^ (rb & 7);
          bfr[f][kk] = *(const f16x8*)&Ws[rb * 64 + cb * 8];
        }
      #pragma unroll
      for (int kk = 0; kk < 2; ++kk)
        #pragma unroll
        for (int fm = 0; fm < 4; ++fm)
          #pragma unroll
          for (int fn = 0; fn < 4; ++fn)
            acc[fm][fn] = __builtin_amdgcn_mfma_f32_16x16x32_f16(
                af[fm][kk], bfr[fn][kk], acc[fm][fn], 0, 0, 0);
    }

    #pragma unroll
    for (int fm = 0; fm < 4; ++fm) {
      const int m = row0 + wr * 64 + fm * 16 + (lane >> 4) * 4;
      #pragma unroll
      for (int fn = 0; fn < 4; ++fn) {
        const int c = col0 + wc * 64 + fn * 16 + (lane & 15);
        const float bv = bias[c];
        #pragma unroll
        for (int r = 0; r < 4; ++r)
          C[(size_t)(m + r) * NC + c] = f2h(acc[fm][fn][r] + bv);
      }
    }
  }
}

// -------- final GEMM: out = acc(MQ,512 f16) @ Wfin^T + bfin, fp32 out ----------
__global__ __launch_bounds__(256)
void gemm_final(const unsigned short* __restrict__ A,
                const unsigned short* __restrict__ W,
                const float* __restrict__ bias, float* __restrict__ out) {
  __shared__ __align__(16) unsigned short As[128 * 64];
  __shared__ __align__(16) unsigned short Ws[128 * 64];
  const int t    = threadIdx.x;
  const int lane = t & 63;
  const int wv   = t >> 6;
  const int wr   = wv >> 1, wc = wv & 1;
  const int row0 = blockIdx.x * 128, col0 = blockIdx.y * 128;
  const int srow = t >> 3, schunk = t & 7;
  const int wbase = wv * 512;

  f32x4 acc[4][4] = {};

  for (int k0 = 0; k0 < 512; k0 += 64) {
    __syncthreads();
    #pragma unroll
    for (int i = 0; i < 4; ++i) {
      const int row = i * 32 + srow;
      const int ch  = schunk ^ (row & 7);
      GLD16(A + (size_t)(row0 + row) * 512 + k0 + ch * 8, &As[i * 2048 + wbase]);
      GLD16(W + (size_t)(col0 + row) * 512 + k0 + ch * 8, &Ws[i * 2048 + wbase]);
    }
    __syncthreads();

    f16x8 af[4][2], bfr[4][2];
    #pragma unroll
    for (int f = 0; f < 4; ++f)
      #pragma unroll
      for (int kk = 0; kk < 2; ++kk) {
        const int ra = wr * 64 + f * 16 + (lane & 15);
        const int ca = (kk * 4 + (lane >> 4)) ^ (ra & 7);
        af[f][kk] = *(const f16x8*)&As[ra * 64 + ca * 8];
        const int rb = wc * 64 + f * 16 + (lane & 15);
        const int cb = (kk * 4 + (lane >> 4)) ^ (rb & 7);
        bfr[f][kk] = *(const f16x8*)&Ws[rb * 64 + cb * 8];
      }
    #pragma unroll
    for (int kk = 0; kk < 2; ++kk)
      #pragma unroll
      for (int fm = 0; fm < 4; ++fm)
        #pragma unroll
        for (int fn = 0; fn < 4; ++fn)
          acc[fm][fn] = __builtin_amdgcn_mfma_f32_16x16x32_f16(
              af[fm][kk], bfr[fn][kk], acc[fm][fn], 0, 0, 0);
  }

  #pragma unroll
  for (int fm = 0; fm < 4; ++fm) {
    const int m = row0 + wr * 64 + fm * 16 + (lane >> 4) * 4;
    #pragma unroll
    for (int fn = 0; fn < 4; ++fn) {
      const int c = col0 + wc * 64 + fn * 16 + (lane & 15);
      const float bv = bias[c];
      #pragma unroll
      for (int r = 0; r < 4; ++r)
        out[(size_t)(m + r) * 256 + c] = acc[fm][fn][r] + bv;
    }
  }
}

// ------------------------- deformable sampling (both streams) ------------------
// grid 5440 x 256 threads = 8 queries x 32 lanes per block.
// XCD-locality: sn = blockIdx.x & 7 selects (stream, batch) -> with round-robin
// block->XCD dispatch, each XCD touches exactly ONE 2.78 MB value slab (L2-fit).
// Phase 1: softmax via 2 shfl_xor; pack per point ONE uint4 {idx01,idx23,w01,w23}
//   (16-bit row indices) at lds[q][j][h^(j&7)] -> 16 KB.
// Phase 2: per level-group: issue ALL 16 f16x8 gathers, sched_barrier(0) to pin
//   them in flight, then consume with v_pk_fma_f16.
__global__ __launch_bounds__(256, 4)
void deform_sample7(const unsigned short* __restrict__ vals,  // (2,N,LQ,256) f16
                    const unsigned short* __restrict__ oa,    // (2,MQ,384) f16
                    const float* __restrict__ refp,           // (N,LQ,4,2) f32
                    unsigned short* __restrict__ acc_out) {   // (MQ,512) f16
  const int bid = blockIdx.x;
  const int sn  = bid & 7;                // -> XCD k holds slab k
  const int s   = sn >> 2, n = sn & 3;
  const int qb  = bid >> 3;               // 0..679 within (s,n)
  const int t   = threadIdx.x;
  const int q   = t >> 5, tq = t & 31;
  const int row = n * LQ_ + qb * 8 + q;
  const int h   = tq >> 2;
  __shared__ uint4 lds_rec[8][16][8];   // 16 KB: {idx01, idx23, w01, w23}

  const unsigned short* oar = oa + ((size_t)s * MQ_ + row) * 384;
  {
    const int   l  = tq & 3;
    const int   Wn = 64 >> l;
    const float Wf = (float)Wn;
    const int   lb = (int)(((0xAD200u >> (5 * l)) & 31u) << 8);  // {0,4096,5120,5376}
    const uint4 ov = *reinterpret_cast<const uint4*>(oar + (size_t)tq * 8);
    const uint2 lv = *reinterpret_cast<const uint2*>(oar + 256 + (size_t)tq * 4);
    const float2 rxy = *reinterpret_cast<const float2*>(refp + (size_t)row * 8 + l * 2);
    float lg[4] = { h2f(lv.x), h2f(lv.x >> 16), h2f(lv.y), h2f(lv.y >> 16) };
    float mx = fmaxf(fmaxf(lg[0], lg[1]), fmaxf(lg[2], lg[3]));
    mx = fmaxf(mx, __shfl_xor(mx, 1));
    mx = fmaxf(mx, __shfl_xor(mx, 2));
    float e[4], se;
    #pragma unroll
    for (int k = 0; k < 4; ++k) e[k] = __expf(lg[k] - mx);
    se = (e[0] + e[1]) + (e[2] + e[3]);
    se += __shfl_xor(se, 1);
    se += __shfl_xor(se, 2);
    const float inv = 1.f / se;
    const unsigned od[4] = { ov.x, ov.y, ov.z, ov.w };
    #pragma unroll
    for (int k = 0; k < 4; ++k) {
      const float ox = h2f(od[k]), oy = h2f(od[k] >> 16);
      const float x = fmaf(rxy.x, Wf, ox) - 0.5f;
      const float y = fmaf(rxy.y, Wf, oy) - 0.5f;
      const float x0f = floorf(x), y0f = floorf(y);
      const int   x0 = (int)x0f,   y0 = (int)y0f;
      const float lx = x - x0f,    ly = y - y0f;
      const float aw = e[k] * inv;
      const int   xs[2] = {x0, x0 + 1}, ys[2] = {y0, y0 + 1};
      const float wx[2] = {1.f - lx, lx}, wy[2] = {1.f - ly, ly};
      unsigned ia[4]; unsigned short wa[4];
      #pragma unroll
      for (int cy = 0; cy < 2; ++cy)
        #pragma unroll
        for (int cx = 0; cx < 2; ++cx) {
          const int xi = xs[cx], yi = ys[cy];
          const bool v = (xi >= 0) && (xi < Wn) && (yi >= 0) && (yi < Wn);
          const int xc = min(max(xi, 0), Wn - 1), yc = min(max(yi, 0), Wn - 1);
          ia[cy * 2 + cx] = (unsigned)(lb + yc * Wn + xc);       // 16-bit row idx
          wa[cy * 2 + cx] = f2h(v ? wx[cx] * wy[cy] * aw : 0.f);
        }
      const int jj = l * 4 + k;
      uint4 rec;
      rec.x = ia[0] | (ia[1] << 16);
      rec.y = ia[2] | (ia[3] << 16);
      rec.z = (unsigned)wa[0] | ((unsigned)wa[1] << 16);
      rec.w = (unsigned)wa[2] | ((unsigned)wa[3] << 16);
      lds_rec[q][jj][h ^ (jj & 7)] = rec;
    }
  }
  __syncthreads();

  const int dg = tq & 3;
  const char* vb = (const char*)(vals + ((size_t)s * N_ + n) * LQ_ * 256);
  const unsigned hd = (unsigned)((h * 32 + dg * 8) * 2);   // byte offset in row
  float facc[8] = {};
  #pragma unroll 1
  for (int l4 = 0; l4 < 4; ++l4) {
    uint4 m[4];
    #pragma unroll
    for (int p = 0; p < 4; ++p) {
      const int j = l4 * 4 + p;
      m[p] = lds_rec[q][j][h ^ (j & 7)];
    }
    f16x8 v[16];
    #pragma unroll
    for (int p = 0; p < 4; ++p) {
      v[p * 4 + 0] = *reinterpret_cast<const f16x8*>(vb + (((m[p].x & 0xffffu) << 9) + hd));
      v[p * 4 + 1] = *reinterpret_cast<const f16x8*>(vb + (((m[p].x >> 16) << 9) + hd));
      v[p * 4 + 2] = *reinterpret_cast<const f16x8*>(vb + (((m[p].y & 0xffffu) << 9) + hd));
      v[p * 4 + 3] = *reinterpret_cast<const f16x8*>(vb + (((m[p].y >> 16) << 9) + hd));
    }
    __builtin_amdgcn_sched_barrier(0);   // keep all 16 gathers in flight
    f16x2 a0 = {0, 0}, a1 = {0, 0}, a2 = {0, 0}, a3 = {0, 0};
    #pragma unroll
    for (int p = 0; p < 4; ++p) {
      const f16x2 w0 = u2h2(__builtin_amdgcn_perm(m[p].z, m[p].z, 0x01000100u));
      const f16x2 w1 = u2h2(__builtin_amdgcn_perm(m[p].z, m[p].z, 0x03020302u));
      const f16x2 w2 = u2h2(__builtin_amdgcn_perm(m[p].w, m[p].w, 0x01000100u));
      const f16x2 w3 = u2h2(__builtin_amdgcn_perm(m[p].w, m[p].w, 0x03020302u));
      const f16x2* p0 = (const f16x2*)&v[p * 4 + 0];
      const f16x2* p1 = (const f16x2*)&v[p * 4 + 1];
      const f16x2* p2 = (const f16x2*)&v[p * 4 + 2];
      const f16x2* p3 = (const f16x2*)&v[p * 4 + 3];
      a0 = __builtin_elementwise_fma(p0[0], w0, a0);
      a1 = __builtin_elementwise_fma(p0[1], w0, a1);
      a2 = __builtin_elementwise_fma(p0[2], w0, a2);
      a3 = __builtin_elementwise_fma(p0[3], w0, a3);
      a0 = __builtin_elementwise_fma(p1[0], w1, a0);
      a1 = __builtin_elementwise_fma(p1[1], w1, a1);
      a2 = __builtin_elementwise_fma(p1[2], w1, a2);
      a3 = __builtin_elementwise_fma(p1[3], w1, a3);
      a0 = __builtin_elementwise_fma(p2[0], w2, a0);
      a1 = __builtin_elementwise_fma(p2[1], w2, a1);
      a2 = __builtin_elementwise_fma(p2[2], w2, a2);
      a3 = __builtin_elementwise_fma(p2[3], w2, a3);
      a0 = __builtin_elementwise_fma(p3[0], w3, a0);
      a1 = __builtin_elementwise_fma(p3[1], w3, a1);
      a2 = __builtin_elementwise_fma(p3[2], w3, a2);
      a3 = __builtin_elementwise_fma(p3[3], w3, a3);
    }
    facc[0] += (float)a0[0]; facc[1] += (float)a0[1];
    facc[2] += (float)a1[0]; facc[3] += (float)a1[1];
    facc[4] += (float)a2[0]; facc[5] += (float)a2[1];
    facc[6] += (float)a3[0]; facc[7] += (float)a3[1];
  }
  f16x8 r;
  #pragma unroll
  for (int e2 = 0; e2 < 8; ++e2) r[e2] = (f16)facc[e2];
  *reinterpret_cast<f16x8*>(acc_out + (size_t)row * 512 + s * 256 + h * 32 + dg * 8) = r;
}

// -------------------------------- launcher -------------------------------------
extern "C" void kernel_launch(void* const* d_in, const int* in_sizes, int n_in,
                              void* d_out, int out_size, void* d_ws, size_t ws_size,
                              hipStream_t stream) {
  const float* query0 = (const float*)d_in[0];
  const float* query1 = (const float*)d_in[1];
  const float* feat0  = (const float*)d_in[2];
  const float* feat1  = (const float*)d_in[3];
  const float* refp   = (const float*)d_in[4];
  const float* W_off  = (const float*)d_in[5];
  const float* b_off  = (const float*)d_in[6];
  const float* W_attn = (const float*)d_in[7];
  const float* b_attn = (const float*)d_in[8];
  const float* W_val  = (const float*)d_in[9];
  const float* b_val  = (const float*)d_in[10];
  const float* W_out  = (const float*)d_in[11];
  const float* b_out  = (const float*)d_in[12];
  const float* W_agg  = (const float*)d_in[13];
  const float* b_agg  = (const float*)d_in[14];
  float* out = (float*)d_out;

  char* p = (char*)d_ws;
  const size_t SZ = (size_t)MQ_ * 256;                 // elems per (MQ,256)
  unsigned short* valb  = (unsigned short*)p; p += 2 * SZ * 2;
  unsigned short* oab   = (unsigned short*)p; p += (size_t)2 * MQ_ * 384 * 2;
  unsigned short* accb  = (unsigned short*)p; p += (size_t)MQ_ * 512 * 2;
  unsigned short* Wvalh = (unsigned short*)p; p += 256 * 256 * 2;
  unsigned short* Wcath = (unsigned short*)p; p += 384 * 256 * 2;
  unsigned short* Wfinh = (unsigned short*)p; p += 256 * 512 * 2;
  float* bcat = (float*)p; p += 384 * 4;
  float* bfin = (float*)p; p += 256 * 4;

  prep<<<675, 256, 0, stream>>>(W_val, W_off, W_attn, W_agg, W_out, b_off, b_attn,
                                b_agg, b_out, Wvalh, Wcath, Wfinh, bcat, bfin);
  // val (src=0) + off/attn (src=1) projections, both streams, col-tiles in-block
  gemm_stage1<<<dim3(170, 2, 2), 256, 0, stream>>>(query0, query1, feat0, feat1,
                                                   Wvalh, Wcath, b_val, bcat,
                                                   valb, oab);
  // sampling, both streams, XCD-local value slabs
  deform_sample7<<<5440, 256, 0, stream>>>(valb, oab, refp, accb);
  // final fused out+agg projection: K=512
  gemm_final<<<dim3(170, 2), 256, 0, stream>>>(accb, Wfinh, bfin, out);
}